// Round 14
// baseline (1776.434 us; speedup 1.0000x reference)
//
#include <hip/hip_runtime.h>
#include <math.h>

#define BB 2
#define CCH 64
#define NN 4096
#define KK 9
#define TT 2
#define C2 128
#define C4 256
#define R1 (BB*NN)        /* 8192  */
#define RG (BB*NN*KK)     /* 73728 */
#define SPLIT 16
#define CHUNK (NN/SPLIT)  /* 256 */
#define JT 64             /* j-tile rows staged in LDS */

#define WS_TOTAL 5194240ull

__device__ __forceinline__ float gelu(float v){ return 0.5f*v*(1.f + erff(v*0.70710678118654752f)); }

__global__ void k_zero(float* __restrict__ o, int n){
  int i = blockIdx.x*256 + threadIdx.x;
  if (i < n) o[i] = 0.f;
}

// ---------------- transpose x (B,C,N) -> x0f (B,N,C) ----------------
__global__ void k_transpose(const float* __restrict__ x, float* __restrict__ x0f){
  int idx = blockIdx.x*256 + threadIdx.x;
  if (idx >= BB*NN*CCH) return;
  int c = idx & (CCH-1);
  int n = (idx >> 6) & (NN-1);
  int b = idx >> 18;
  x0f[idx] = x[(size_t)(b*CCH + c)*NN + n];
}

// ---------------- GEMM1 (64->64) + stats: 256 blocks x 32 rows ----------------
__global__ void k_gemm1_stats(const float* __restrict__ X, const float* __restrict__ W,
                              const float* __restrict__ bias, float* __restrict__ Y,
                              float* __restrict__ part){
  __shared__ float WL[64*64];
  __shared__ float xL[32*64];
  __shared__ float s1[256], s2[256];
  int tid = threadIdx.x;
  int r0 = blockIdx.x*32;
  {
    const float4* ws4 = (const float4*)W;
    float4* wd4 = (float4*)WL;
    #pragma unroll
    for (int u=0; u<4; u++) wd4[u*256+tid] = ws4[u*256+tid];
    const float4* xs4 = (const float4*)(X + (size_t)r0*64);
    float4* xd4 = (float4*)xL;
    #pragma unroll
    for (int u=0; u<2; u++) xd4[u*256+tid] = xs4[u*256+tid];
  }
  __syncthreads();
  int c = tid & 63, rs = tid >> 6;
  float bz = bias[c];
  float sm=0.f, ss=0.f;
  for (int it=0; it<8; it++){
    int lr = it*4 + rs;
    float acc = bz;
    for (int d=0; d<64; d++) acc = fmaf(xL[lr*64+d], WL[d*64+c], acc);
    Y[(size_t)(r0+lr)*64 + c] = acc;
    sm += acc; ss += acc*acc;
  }
  s1[tid]=sm; s2[tid]=ss;
  __syncthreads();
  if (tid < 64){
    sm = s1[tid]+s1[64+tid]+s1[128+tid]+s1[192+tid];
    ss = s2[tid]+s2[64+tid]+s2[128+tid]+s2[192+tid];
    part[blockIdx.x*128 + tid] = sm;
    part[blockIdx.x*128 + 64 + tid] = ss;
  }
}

// ---------------- GEMM2 (128->64) + stats: 256 blocks x 32 rows ----------------
__global__ void k_gemm2_stats(const float* __restrict__ X, const float* __restrict__ W,
                              const float* __restrict__ bias, float* __restrict__ Y,
                              float* __restrict__ part){
  __shared__ float WL[128*64];
  __shared__ float xL[32*128];
  __shared__ float s1[256], s2[256];
  int tid = threadIdx.x;
  int r0 = blockIdx.x*32;
  {
    const float4* ws4 = (const float4*)W;
    float4* wd4 = (float4*)WL;
    #pragma unroll
    for (int u=0; u<8; u++) wd4[u*256+tid] = ws4[u*256+tid];
    const float4* xs4 = (const float4*)(X + (size_t)r0*128);
    float4* xd4 = (float4*)xL;
    #pragma unroll
    for (int u=0; u<4; u++) xd4[u*256+tid] = xs4[u*256+tid];
  }
  __syncthreads();
  int c = tid & 63, rs = tid >> 6;
  float bz = bias[c];
  float sm=0.f, ss=0.f;
  for (int it=0; it<8; it++){
    int lr = it*4 + rs;
    float acc = bz;
    for (int d=0; d<128; d++) acc = fmaf(xL[lr*128+d], WL[d*64+c], acc);
    Y[(size_t)(r0+lr)*64 + c] = acc;
    sm += acc; ss += acc*acc;
  }
  s1[tid]=sm; s2[tid]=ss;
  __syncthreads();
  if (tid < 64){
    sm = s1[tid]+s1[64+tid]+s1[128+tid]+s1[192+tid];
    ss = s2[tid]+s2[64+tid]+s2[128+tid]+s2[192+tid];
    part[blockIdx.x*128 + tid] = sm;
    part[blockIdx.x*128 + 64 + tid] = ss;
  }
}

// ---------------- inline fin (G=256, Cc=64) + BN apply + row-normalize ------------
__global__ void k_applynorm3(float* __restrict__ h, const float* __restrict__ part,
                             const float* __restrict__ g, const float* __restrict__ bt,
                             float* __restrict__ xn, float* __restrict__ sq){
  __shared__ float scshL[128];
  __shared__ float s1[256], s2[256];
  int tid = threadIdx.x;
  {
    int c = tid & 63, sl = tid >> 6;
    float sm=0.f, ss=0.f;
    #pragma unroll 4
    for (int u=sl*64; u<sl*64+64; u++){ sm += part[u*128+c]; ss += part[u*128+64+c]; }
    s1[tid]=sm; s2[tid]=ss;
  }
  __syncthreads();
  if (tid < 64){
    float sm = s1[tid]+s1[64+tid]+s1[128+tid]+s1[192+tid];
    float ss = s2[tid]+s2[64+tid]+s2[128+tid]+s2[192+tid];
    float mean = sm/(float)R1;
    float var = fmaxf(ss/(float)R1 - mean*mean, 0.f);
    float sc = g[tid]*rsqrtf(var+1e-5f);
    scshL[tid] = sc; scshL[64+tid] = bt[tid] - mean*sc;
  }
  __syncthreads();
  int lane = tid & 63, w = tid >> 6;
  int r0 = blockIdx.x*32;
  for (int it=0; it<8; it++){
    int r = r0 + w*8 + it;
    float v = fmaf(h[(size_t)r*64+lane], scshL[lane], scshL[64+lane]);
    h[(size_t)r*64+lane] = v;
    float s2v = v*v;
    #pragma unroll
    for (int off=32; off; off>>=1) s2v += __shfl_xor(s2v, off, 64);
    float den = fmaxf(sqrtf(s2v), 1e-12f);
    float xv = v/den;
    xn[(size_t)r*64+lane] = xv;
    float t2 = xv*xv;
    #pragma unroll
    for (int off=32; off; off>>=1) t2 += __shfl_xor(t2, off, 64);
    if (lane==0) sq[r] = t2;
  }
}

// ---------------- top-9 streaming insert (strict <) ----------------
__device__ __forceinline__ void topk_insert(float d, int j, float* bd, int* bi,
                                            float& wd, int& wi){
  if (d < wd){
    bool done=false;
    #pragma unroll
    for (int q=0;q<9;q++){
      if (!done && bd[q]==wd && bi[q]==wi){ bd[q]=d; bi[q]=j; done=true; }
    }
    wd = bd[0]; wi = bi[0];
    #pragma unroll
    for (int q=1;q<9;q++){
      if (bd[q] > wd || (bd[q]==wd && bi[q] > wi)){ wd=bd[q]; wi=bi[q]; }
    }
  }
}

// ---------------- KNN: 2-lane row pairing; 32-float fragment/lane -----------------
// grid: 2 batches x 32 i-blocks(128 rows) x 16 splits = 1024 blocks (4/CU)
__global__ __launch_bounds__(256, 4) void k_knn(const float* __restrict__ xn,
                      const float* __restrict__ sq,
                      float* __restrict__ pd, int* __restrict__ pi_){
  __shared__ float xjL[JT*64];
  __shared__ float sqL[JT];
  int bx = blockIdx.x;
  if (bx >= 1024) return;
  int b     = bx >> 9;
  int ib    = (bx >> 4) & 31;
  int split = bx & 15;
  int tid = threadIdx.x;
  int pr = tid >> 1;          // pair id 0..127 (row within block)
  int s  = tid & 1;           // which 32-dim half this lane owns
  const float* xb = xn + (size_t)b*NN*64;
  const float* sqb = sq + (size_t)b*NN;
  int i = ib*128 + pr;
  float4 xi[8];
  {
    const float4* p = (const float4*)(xb + (size_t)i*64 + s*32);
    #pragma unroll
    for (int q=0;q<8;q++) xi[q] = p[q];
  }
  #pragma unroll
  for (int q=0;q<8;q++){
    asm volatile("" : "+v"(xi[q].x), "+v"(xi[q].y), "+v"(xi[q].z), "+v"(xi[q].w));
  }
  float sqi = sqb[i];
  float bd[9]; int bi[9];
  #pragma unroll
  for (int q=0;q<9;q++){ bd[q]=INFINITY; bi[q]=0x7fffffff; }
  float wd=INFINITY; int wi=0x7fffffff;
  int jbase = split*CHUNK;
  for (int tile=0; tile<CHUNK/JT; tile++){
    int jt = jbase + tile*JT;
    __syncthreads();
    {
      const float4* src = (const float4*)(xb + (size_t)jt*64);
      float4* dst = (float4*)xjL;
      #pragma unroll
      for (int u=0; u<4; u++) dst[u*256 + tid] = src[u*256 + tid];
      if (tid < JT) sqL[tid] = sqb[jt + tid];
    }
    __syncthreads();
    for (int jj=0; jj<JT; jj++){
      const float4* xj = (const float4*)(xjL + jj*64 + s*32);
      float a0=0.f,a1=0.f,a2=0.f,a3=0.f;
      #pragma unroll
      for (int q=0;q<8;q++){
        float4 v = xj[q];
        a0 = fmaf(xi[q].x, v.x, a0);
        a1 = fmaf(xi[q].y, v.y, a1);
        a2 = fmaf(xi[q].z, v.z, a2);
        a3 = fmaf(xi[q].w, v.w, a3);
      }
      float dhalf = (a0+a1)+(a2+a3);
      float dot = dhalf + __shfl_xor(dhalf, 1, 64);   // commutative add: both lanes identical
      int j = jt + jj;
      float d = sqi + sqL[jj] - 2.f*dot;
      topk_insert(d, j, bd, bi, wd, wi);
    }
  }
  if (s == 0){
    size_t base = (((size_t)(b*NN + i))*SPLIT + split)*9;
    #pragma unroll
    for (int q=0;q<9;q++){ pd[base+q]=bd[q]; pi_[base+q]=bi[q]; }
  }
}

// ------- edge pass 1: fused merge + edge-GEMM stats; wave-private, barrier-free -----
__global__ __launch_bounds__(256) void k_edge1(const float* __restrict__ h,
                        const float* __restrict__ pd, const int* __restrict__ pi_,
                        const float* __restrict__ Wg, const float* __restrict__ bg,
                        int* __restrict__ idxf, float* __restrict__ part){
  __shared__ float dxAll[4*576];
  __shared__ float xiAll[4*64];
  __shared__ float sSum[512], sSq[512];
  int tid = threadIdx.x, lane = tid & 63, wv = tid >> 6;
  float* dxW = dxAll + wv*576;
  float* xiW = xiAll + wv*64;
  int c0 = lane, c1 = lane + 64;
  float bias0 = bg[c0], bias1 = bg[c1];
  float sm0=0.f, ss0=0.f, sm1=0.f, ss1=0.f;
  for (int u4=0; u4<4; u4++){
    int node = blockIdx.x*16 + wv*4 + u4;
    int b = node >> 12;
    size_t cb = (size_t)node*(SPLIT*9);
    float d0 = pd[cb+lane], d1 = pd[cb+64+lane], d2 = INFINITY;
    int   j0 = pi_[cb+lane], j1 = pi_[cb+64+lane], j2 = 0x7fffffff;
    if (lane < 16){ d2 = pd[cb+128+lane]; j2 = pi_[cb+128+lane]; }
    int kidx[9];
    #pragma unroll
    for (int s=0; s<9; s++){
      float ld = d0; int lj = j0;
      if (d1 < ld || (d1 == ld && j1 < lj)){ ld = d1; lj = j1; }
      if (d2 < ld || (d2 == ld && j2 < lj)){ ld = d2; lj = j2; }
      #pragma unroll
      for (int off=1; off<64; off<<=1){
        float od = __shfl_xor(ld, off, 64);
        int   oj = __shfl_xor(lj, off, 64);
        if (od < ld || (od == ld && oj < lj)){ ld = od; lj = oj; }
      }
      kidx[s] = lj & (NN-1);
      if (lane == 0) idxf[(size_t)node*9 + s] = lj & (NN-1);
      if (j0 == lj){ d0 = INFINITY; j0 = 0x7fffffff; }
      if (j1 == lj){ d1 = INFINITY; j1 = 0x7fffffff; }
      if (j2 == lj){ d2 = INFINITY; j2 = 0x7fffffff; }
    }
    float xi_l = h[(size_t)node*64 + lane];
    xiW[lane] = xi_l;
    #pragma unroll
    for (int k=0; k<9; k++)
      dxW[k*64+lane] = h[((size_t)(b*NN + kidx[k]))*64 + lane] - xi_l;
    float common0 = bias0, common1 = bias1;
    for (int d=0; d<64; d++){
      float xv = xiW[d];
      common0 = fmaf(xv, Wg[d*C2+c0], common0);
      common1 = fmaf(xv, Wg[d*C2+c1], common1);
    }
    float a0[9], a1[9];
    #pragma unroll
    for (int k=0;k<9;k++){ a0[k]=0.f; a1[k]=0.f; }
    for (int d=0; d<64; d++){
      float w0 = Wg[(64+d)*C2+c0], w1 = Wg[(64+d)*C2+c1];
      #pragma unroll
      for (int k=0;k<9;k++){
        float dxv = dxW[k*64+d];
        a0[k] = fmaf(dxv, w0, a0[k]);
        a1[k] = fmaf(dxv, w1, a1[k]);
      }
    }
    #pragma unroll
    for (int k=0;k<9;k++){
      float v0 = common0 + a0[k], v1 = common1 + a1[k];
      sm0 += v0; ss0 += v0*v0; sm1 += v1; ss1 += v1*v1;
    }
  }
  sSum[wv*128+lane] = sm0; sSum[wv*128+64+lane] = sm1;
  sSq [wv*128+lane] = ss0; sSq [wv*128+64+lane] = ss1;
  __syncthreads();
  if (tid < 128){
    float sm = sSum[tid]+sSum[128+tid]+sSum[256+tid]+sSum[384+tid];
    float ss = sSq[tid]+sSq[128+tid]+sSq[256+tid]+sSq[384+tid];
    part[blockIdx.x*256 + tid] = sm;
    part[blockIdx.x*256 + 128 + tid] = ss;
  }
}

// ------- edge pass 2: inline fin (G=512,Cc=128) + recompute + BN + gelu + max ------
__global__ __launch_bounds__(256) void k_edge2(const float* __restrict__ h,
                        const int* __restrict__ idxf,
                        const float* __restrict__ Wg, const float* __restrict__ bg,
                        const float* __restrict__ part, const float* __restrict__ gg,
                        const float* __restrict__ btg, float* __restrict__ gmax){
  __shared__ float dxAll[4*576];
  __shared__ float xiAll[4*64];
  __shared__ float scshL[256];
  __shared__ float s1[256], s2[256];
  int tid = threadIdx.x, lane = tid & 63, wv = tid >> 6;
  {
    int cc = tid & 127, sl = tid >> 7;
    float sm=0.f, ss=0.f;
    #pragma unroll 4
    for (int u=sl*256; u<sl*256+256; u++){ sm += part[u*256+cc]; ss += part[u*256+128+cc]; }
    s1[tid]=sm; s2[tid]=ss;
  }
  __syncthreads();
  if (tid < 128){
    float sm = s1[tid]+s1[128+tid];
    float ss = s2[tid]+s2[128+tid];
    float mean = sm/(float)RG;
    float var = fmaxf(ss/(float)RG - mean*mean, 0.f);
    float sc = gg[tid]*rsqrtf(var+1e-5f);
    scshL[tid] = sc; scshL[128+tid] = btg[tid] - mean*sc;
  }
  __syncthreads();
  float* dxW = dxAll + wv*576;
  float* xiW = xiAll + wv*64;
  int c0 = lane, c1 = lane + 64;
  float bias0 = bg[c0], bias1 = bg[c1];
  float sc0 = scshL[c0], sh0 = scshL[128+c0];
  float sc1 = scshL[c1], sh1 = scshL[128+c1];
  for (int u4=0; u4<4; u4++){
    int node = blockIdx.x*16 + wv*4 + u4;
    int b = node >> 12;
    int kidx[9];
    #pragma unroll
    for (int k=0;k<9;k++) kidx[k] = idxf[(size_t)node*9 + k] & (NN-1);
    float xi_l = h[(size_t)node*64 + lane];
    xiW[lane] = xi_l;
    #pragma unroll
    for (int k=0; k<9; k++)
      dxW[k*64+lane] = h[((size_t)(b*NN + kidx[k]))*64 + lane] - xi_l;
    float common0 = bias0, common1 = bias1;
    for (int d=0; d<64; d++){
      float xv = xiW[d];
      common0 = fmaf(xv, Wg[d*C2+c0], common0);
      common1 = fmaf(xv, Wg[d*C2+c1], common1);
    }
    float a0[9], a1[9];
    #pragma unroll
    for (int k=0;k<9;k++){ a0[k]=0.f; a1[k]=0.f; }
    for (int d=0; d<64; d++){
      float w0 = Wg[(64+d)*C2+c0], w1 = Wg[(64+d)*C2+c1];
      #pragma unroll
      for (int k=0;k<9;k++){
        float dxv = dxW[k*64+d];
        a0[k] = fmaf(dxv, w0, a0[k]);
        a1[k] = fmaf(dxv, w1, a1[k]);
      }
    }
    float m0 = -INFINITY, m1 = -INFINITY;
    #pragma unroll
    for (int k=0;k<9;k++){
      m0 = fmaxf(m0, gelu(fmaf(common0 + a0[k], sc0, sh0)));
      m1 = fmaxf(m1, gelu(fmaf(common1 + a1[k], sc1, sh1)));
    }
    gmax[(size_t)node*C2 + c0] = m0;
    gmax[(size_t)node*C2 + c1] = m1;
  }
}

// ------- inline fin(G=256,Cc=64) + BN2 + residual + FFN1 GEMM + stats --------------
__global__ void k_ffn1_fused(const float* __restrict__ Y2, const float* __restrict__ part,
                             const float* __restrict__ g2, const float* __restrict__ bt2,
                             const float* __restrict__ x0f, float* __restrict__ outt,
                             const float* __restrict__ Wf1, const float* __restrict__ bf1,
                             float* __restrict__ partB){
  __shared__ float scshL[128];
  __shared__ float otL[32*64];
  __shared__ float WL[64*256];
  __shared__ float s1[256], s2[256];
  int tid = threadIdx.x;
  int r0 = blockIdx.x*32;
  {
    const float4* s4 = (const float4*)Wf1; float4* d4 = (float4*)WL;
    #pragma unroll
    for (int u=0; u<16; u++) d4[u*256+tid] = s4[u*256+tid];
  }
  {
    int c = tid & 63, sl = tid >> 6;
    float sm=0.f, ss=0.f;
    #pragma unroll 4
    for (int u=sl*64; u<sl*64+64; u++){ sm += part[u*128+c]; ss += part[u*128+64+c]; }
    s1[tid]=sm; s2[tid]=ss;
  }
  __syncthreads();
  if (tid < 64){
    float sm = s1[tid]+s1[64+tid]+s1[128+tid]+s1[192+tid];
    float ss = s2[tid]+s2[64+tid]+s2[128+tid]+s2[192+tid];
    float mean = sm/(float)R1;
    float var = fmaxf(ss/(float)R1 - mean*mean, 0.f);
    float sc = g2[tid]*rsqrtf(var+1e-5f);
    scshL[tid] = sc; scshL[64+tid] = bt2[tid] - mean*sc;
  }
  __syncthreads();
  for (int p=0; p<8; p++){
    int idx = p*256 + tid;
    int lr = idx >> 6, cc = idx & 63;
    size_t gi = (size_t)(r0+lr)*64 + cc;
    float v = fmaf(Y2[gi], scshL[cc], scshL[64+cc]) + x0f[gi];
    otL[idx] = v; outt[gi] = v;
  }
  __syncthreads();
  float bias = bf1[tid];
  float sm=0.f, ss=0.f;
  for (int lr=0; lr<32; lr++){
    float acc = bias;
    for (int d=0; d<64; d++) acc = fmaf(otL[lr*64+d], WL[d*256+tid], acc);
    sm += acc; ss += acc*acc;
  }
  partB[blockIdx.x*512 + tid] = sm;
  partB[blockIdx.x*512 + 256 + tid] = ss;
}

// ------- inline fin(G=256,Cc=256) + FFN1-recompute + gelu + FFN2 GEMM + stats ------
__global__ void k_ffn2_fused(const float* __restrict__ outt, const float* __restrict__ Wf1,
                             const float* __restrict__ bf1, const float* __restrict__ partB,
                             const float* __restrict__ gf1, const float* __restrict__ btf1,
                             const float* __restrict__ Wf2, const float* __restrict__ bf2,
                             float* __restrict__ Yf2, float* __restrict__ partA){
  __shared__ float scshL[512];
  __shared__ float otL[32*64];
  __shared__ float fLL[32*256];
  __shared__ float s1[256], s2[256];
  int tid = threadIdx.x;
  int r0 = blockIdx.x*32;
  {
    float sm=0.f, ss=0.f;
    #pragma unroll 4
    for (int u=0; u<256; u++){ sm += partB[u*512+tid]; ss += partB[u*512+256+tid]; }
    float mean = sm/(float)R1;
    float var = fmaxf(ss/(float)R1 - mean*mean, 0.f);
    float sc = gf1[tid]*rsqrtf(var+1e-5f);
    scshL[tid] = sc; scshL[256+tid] = btf1[tid] - mean*sc;
  }
  for (int p=0; p<8; p++){
    int idx = p*256 + tid;
    otL[idx] = outt[(size_t)r0*64 + idx];
  }
  __syncthreads();
  float bias = bf1[tid];
  for (int lr=0; lr<32; lr++){
    float acc = bias;
    for (int d=0; d<64; d++) acc = fmaf(otL[lr*64+d], Wf1[d*256+tid], acc);
    float v = fmaf(acc, scshL[tid], scshL[256+tid]);
    fLL[lr*256+tid] = gelu(v);
  }
  __syncthreads();
  int c = tid & 63, rs = tid >> 6;
  float b2z = bf2[c];
  float sm=0.f, ss=0.f;
  for (int it=0; it<8; it++){
    int lr = it*4 + rs;
    float acc = b2z;
    for (int d=0; d<256; d++) acc = fmaf(fLL[lr*256+d], Wf2[d*64+c], acc);
    Yf2[(size_t)(r0+lr)*64 + c] = acc;
    sm += acc; ss += acc*acc;
  }
  s1[tid]=sm; s2[tid]=ss;
  __syncthreads();
  if (tid < 64){
    sm = s1[tid]+s1[64+tid]+s1[128+tid]+s1[192+tid];
    ss = s2[tid]+s2[64+tid]+s2[128+tid]+s2[192+tid];
    partA[blockIdx.x*128 + tid] = sm;
    partA[blockIdx.x*128 + 64 + tid] = ss;
  }
}

// ---------------- inline fin(G=256,Cc=64) + BNf2 + residual -> feats[t] ------------
__global__ void k_final(const float* __restrict__ Yf2, const float* __restrict__ partA,
                        const float* __restrict__ gf2, const float* __restrict__ btf2,
                        const float* __restrict__ outt, float* __restrict__ feat){
  __shared__ float scshL[128];
  __shared__ float s1[256], s2[256];
  int tid = threadIdx.x;
  {
    int c = tid & 63, sl = tid >> 6;
    float sm=0.f, ss=0.f;
    #pragma unroll 4
    for (int u=sl*64; u<sl*64+64; u++){ sm += partA[u*128+c]; ss += partA[u*128+64+c]; }
    s1[tid]=sm; s2[tid]=ss;
  }
  __syncthreads();
  if (tid < 64){
    float sm = s1[tid]+s1[64+tid]+s1[128+tid]+s1[192+tid];
    float ss = s2[tid]+s2[64+tid]+s2[128+tid]+s2[192+tid];
    float mean = sm/(float)R1;
    float var = fmaxf(ss/(float)R1 - mean*mean, 0.f);
    float sc = gf2[tid]*rsqrtf(var+1e-5f);
    scshL[tid] = sc; scshL[64+tid] = btf2[tid] - mean*sc;
  }
  __syncthreads();
  size_t base = (size_t)blockIdx.x*2048;
  for (int p=0; p<8; p++){
    size_t idx = base + p*256 + tid;
    int cc = idx & 63;
    feat[idx] = fmaf(Yf2[idx], scshL[cc], scshL[64+cc]) + outt[idx];
  }
}

// ---------------- alpha-mix + transpose -> output (T,B,C,N) fp32 ----------------
__global__ void k_mix(const float* __restrict__ f0, const float* __restrict__ f1,
                      const float* __restrict__ alpha, float* __restrict__ outv){
  int idx = blockIdx.x*256 + threadIdx.x;
  if (idx >= TT*BB*CCH*NN) return;
  int n = idx & (NN-1);
  int c = (idx >> 12) & 63;
  int b = (idx >> 18) & 1;
  int i = idx >> 19;
  float a0 = alpha[i*TT + 0];
  float a1 = alpha[i*TT + 1];
  size_t fi = ((size_t)(b*NN + n))*64 + c;
  outv[idx] = a0*f0[fi] + a1*f1[fi];
}

extern "C" void kernel_launch(void* const* d_in, const int* in_sizes, int n_in,
                              void* d_out, int out_size, void* d_ws, size_t ws_size,
                              hipStream_t stream){
  float* outp = (float*)d_out;

  static const int expect[22] = {
    524288, 8192, 128, 128, 128, 32768, 256, 256, 256, 16384, 128, 128, 128,
    32768, 512, 512, 512, 32768, 128, 128, 128, 4
  };
  bool ok = (n_in == 22) && (out_size == TT*BB*CCH*NN) &&
            (ws_size >= WS_TOTAL*sizeof(float));
  if (ok){
    for (int i=0;i<22;i++) if (in_sizes[i] != expect[i]) { ok = false; break; }
  }
  if (!ok){
    k_zero<<<(out_size+255)/256,256,0,stream>>>(outp, out_size);
    return;
  }

  const float* x   = (const float*)d_in[0];
  const float* W1  = (const float*)d_in[1];
  const float* b1  = (const float*)d_in[2];
  const float* g1  = (const float*)d_in[3];
  const float* bt1 = (const float*)d_in[4];
  const float* Wg  = (const float*)d_in[5];
  const float* bg  = (const float*)d_in[6];
  const float* gg  = (const float*)d_in[7];
  const float* btg = (const float*)d_in[8];
  const float* W2  = (const float*)d_in[9];
  const float* b2v = (const float*)d_in[10];
  const float* g2  = (const float*)d_in[11];
  const float* bt2 = (const float*)d_in[12];
  const float* Wf1 = (const float*)d_in[13];
  const float* bf1v= (const float*)d_in[14];
  const float* gf1 = (const float*)d_in[15];
  const float* btf1= (const float*)d_in[16];
  const float* Wf2 = (const float*)d_in[17];
  const float* bf2v= (const float*)d_in[18];
  const float* gf2 = (const float*)d_in[19];
  const float* btf2= (const float*)d_in[20];
  const float* alpha=(const float*)d_in[21];
  float* ws = (float*)d_ws;

  float* x0f  = ws + 0;
  float* hbuf = ws + 524288;
  float* xnb  = ws + 1048576;
  float* sqb  = ws + 1572864;
  float* partA= ws + 1581056;
  int*   idxf = (int*)(ws + 1712640);
  float* f0   = ws + 1786368;
  float* f1b  = ws + 2310656;
  float* Rbig = ws + 2834944;
  float* pdist = Rbig;
  int*   pidx  = (int*)(Rbig + (size_t)R1*SPLIT*9);
  float* gmaxb = Rbig;
  float* outt  = Rbig + 1048576;
  float* Y2    = Rbig + 1572864;
  float* partB = Rbig + 2097152;
  float* Yf2   = Rbig;

  k_transpose<<<2048,256,0,stream>>>(x, x0f);
  float* feats[2] = {f0, f1b};
  for (int t=0; t<TT; t++){
    k_gemm1_stats<<<256,256,0,stream>>>(x0f, W1 + t*CCH*CCH, b1 + t*64, hbuf, partA);
    k_applynorm3<<<256,256,0,stream>>>(hbuf, partA, g1 + t*64, bt1 + t*64, xnb, sqb);
    k_knn<<<1024,256,0,stream>>>(xnb, sqb, pdist, pidx);
    k_edge1<<<512,256,0,stream>>>(hbuf, pdist, pidx, Wg + t*C2*C2, bg + t*C2, idxf, partA);
    k_edge2<<<512,256,0,stream>>>(hbuf, idxf, Wg + t*C2*C2, bg + t*C2,
                                  partA, gg + t*C2, btg + t*C2, gmaxb);
    k_gemm2_stats<<<256,256,0,stream>>>(gmaxb, W2 + t*C2*CCH, b2v + t*64, Y2, partA);
    k_ffn1_fused<<<256,256,0,stream>>>(Y2, partA, g2 + t*64, bt2 + t*64, x0f, outt,
                                       Wf1 + t*CCH*C4, bf1v + t*C4, partB);
    k_ffn2_fused<<<256,256,0,stream>>>(outt, Wf1 + t*CCH*C4, bf1v + t*C4, partB,
                                       gf1 + t*C4, btf1 + t*C4,
                                       Wf2 + t*C4*CCH, bf2v + t*64, Yf2, partA);
    k_final<<<256,256,0,stream>>>(Yf2, partA, gf2 + t*64, btf2 + t*64, outt, feats[t]);
  }
  k_mix<<<4096,256,0,stream>>>(f0, f1b, alpha, outp);
}

// Round 15
// 1515.105 us; speedup vs baseline: 1.1725x; 1.1725x over previous
//
#include <hip/hip_runtime.h>
#include <math.h>

#define BB 2
#define CCH 64
#define NN 4096
#define KK 9
#define TT 2
#define C2 128
#define C4 256
#define R1 (BB*NN)        /* 8192  */
#define RG (BB*NN*KK)     /* 73728 */
#define SPLIT 16
#define CHUNK (NN/SPLIT)  /* 256 */
#define JT 128            /* j-tile rows staged in LDS */

#define WS_TOTAL 5194240ull

__device__ __forceinline__ float gelu(float v){ return 0.5f*v*(1.f + erff(v*0.70710678118654752f)); }

__global__ void k_zero(float* __restrict__ o, int n){
  int i = blockIdx.x*256 + threadIdx.x;
  if (i < n) o[i] = 0.f;
}

// ---------------- transpose x (B,C,N) -> x0f (B,N,C) ----------------
__global__ void k_transpose(const float* __restrict__ x, float* __restrict__ x0f){
  int idx = blockIdx.x*256 + threadIdx.x;
  if (idx >= BB*NN*CCH) return;
  int c = idx & (CCH-1);
  int n = (idx >> 6) & (NN-1);
  int b = idx >> 18;
  x0f[idx] = x[(size_t)(b*CCH + c)*NN + n];
}

// ---------------- GEMM1 (64->64) + stats: 256 blocks x 32 rows ----------------
__global__ void k_gemm1_stats(const float* __restrict__ X, const float* __restrict__ W,
                              const float* __restrict__ bias, float* __restrict__ Y,
                              float* __restrict__ part){
  __shared__ float WL[64*64];
  __shared__ float xL[32*64];
  __shared__ float s1[256], s2[256];
  int tid = threadIdx.x;
  int r0 = blockIdx.x*32;
  {
    const float4* ws4 = (const float4*)W;
    float4* wd4 = (float4*)WL;
    #pragma unroll
    for (int u=0; u<4; u++) wd4[u*256+tid] = ws4[u*256+tid];
    const float4* xs4 = (const float4*)(X + (size_t)r0*64);
    float4* xd4 = (float4*)xL;
    #pragma unroll
    for (int u=0; u<2; u++) xd4[u*256+tid] = xs4[u*256+tid];
  }
  __syncthreads();
  int c = tid & 63, rs = tid >> 6;
  float bz = bias[c];
  float sm=0.f, ss=0.f;
  for (int it=0; it<8; it++){
    int lr = it*4 + rs;
    float acc = bz;
    for (int d=0; d<64; d++) acc = fmaf(xL[lr*64+d], WL[d*64+c], acc);
    Y[(size_t)(r0+lr)*64 + c] = acc;
    sm += acc; ss += acc*acc;
  }
  s1[tid]=sm; s2[tid]=ss;
  __syncthreads();
  if (tid < 64){
    sm = s1[tid]+s1[64+tid]+s1[128+tid]+s1[192+tid];
    ss = s2[tid]+s2[64+tid]+s2[128+tid]+s2[192+tid];
    part[blockIdx.x*128 + tid] = sm;
    part[blockIdx.x*128 + 64 + tid] = ss;
  }
}

// ---------------- GEMM2 (128->64) + stats: 256 blocks x 32 rows ----------------
__global__ void k_gemm2_stats(const float* __restrict__ X, const float* __restrict__ W,
                              const float* __restrict__ bias, float* __restrict__ Y,
                              float* __restrict__ part){
  __shared__ float WL[128*64];
  __shared__ float xL[32*128];
  __shared__ float s1[256], s2[256];
  int tid = threadIdx.x;
  int r0 = blockIdx.x*32;
  {
    const float4* ws4 = (const float4*)W;
    float4* wd4 = (float4*)WL;
    #pragma unroll
    for (int u=0; u<8; u++) wd4[u*256+tid] = ws4[u*256+tid];
    const float4* xs4 = (const float4*)(X + (size_t)r0*128);
    float4* xd4 = (float4*)xL;
    #pragma unroll
    for (int u=0; u<4; u++) xd4[u*256+tid] = xs4[u*256+tid];
  }
  __syncthreads();
  int c = tid & 63, rs = tid >> 6;
  float bz = bias[c];
  float sm=0.f, ss=0.f;
  for (int it=0; it<8; it++){
    int lr = it*4 + rs;
    float acc = bz;
    for (int d=0; d<128; d++) acc = fmaf(xL[lr*128+d], WL[d*64+c], acc);
    Y[(size_t)(r0+lr)*64 + c] = acc;
    sm += acc; ss += acc*acc;
  }
  s1[tid]=sm; s2[tid]=ss;
  __syncthreads();
  if (tid < 64){
    sm = s1[tid]+s1[64+tid]+s1[128+tid]+s1[192+tid];
    ss = s2[tid]+s2[64+tid]+s2[128+tid]+s2[192+tid];
    part[blockIdx.x*128 + tid] = sm;
    part[blockIdx.x*128 + 64 + tid] = ss;
  }
}

// ---------------- inline fin (G=256, Cc=64) + BN apply + row-normalize ------------
__global__ void k_applynorm3(float* __restrict__ h, const float* __restrict__ part,
                             const float* __restrict__ g, const float* __restrict__ bt,
                             float* __restrict__ xn, float* __restrict__ sq){
  __shared__ float scshL[128];
  __shared__ float s1[256], s2[256];
  int tid = threadIdx.x;
  {
    int c = tid & 63, sl = tid >> 6;
    float sm=0.f, ss=0.f;
    #pragma unroll 4
    for (int u=sl*64; u<sl*64+64; u++){ sm += part[u*128+c]; ss += part[u*128+64+c]; }
    s1[tid]=sm; s2[tid]=ss;
  }
  __syncthreads();
  if (tid < 64){
    float sm = s1[tid]+s1[64+tid]+s1[128+tid]+s1[192+tid];
    float ss = s2[tid]+s2[64+tid]+s2[128+tid]+s2[192+tid];
    float mean = sm/(float)R1;
    float var = fmaxf(ss/(float)R1 - mean*mean, 0.f);
    float sc = g[tid]*rsqrtf(var+1e-5f);
    scshL[tid] = sc; scshL[64+tid] = bt[tid] - mean*sc;
  }
  __syncthreads();
  int lane = tid & 63, w = tid >> 6;
  int r0 = blockIdx.x*32;
  for (int it=0; it<8; it++){
    int r = r0 + w*8 + it;
    float v = fmaf(h[(size_t)r*64+lane], scshL[lane], scshL[64+lane]);
    h[(size_t)r*64+lane] = v;
    float s2v = v*v;
    #pragma unroll
    for (int off=32; off; off>>=1) s2v += __shfl_xor(s2v, off, 64);
    float den = fmaxf(sqrtf(s2v), 1e-12f);
    float xv = v/den;
    xn[(size_t)r*64+lane] = xv;
    float t2 = xv*xv;
    #pragma unroll
    for (int off=32; off; off>>=1) t2 += __shfl_xor(t2, off, 64);
    if (lane==0) sq[r] = t2;
  }
}

// ---------------- top-9 streaming insert (strict <) ----------------
__device__ __forceinline__ void topk_insert(float d, int j, float* bd, int* bi,
                                            float& wd, int& wi){
  if (d < wd){
    bool done=false;
    #pragma unroll
    for (int q=0;q<9;q++){
      if (!done && bd[q]==wd && bi[q]==wi){ bd[q]=d; bi[q]=j; done=true; }
    }
    wd = bd[0]; wi = bi[0];
    #pragma unroll
    for (int q=1;q<9;q++){
      if (bd[q] > wd || (bd[q]==wd && bi[q] > wi)){ wd=bd[q]; wi=bi[q]; }
    }
  }
}

// ---------------- KNN: 1 i-row/thread (R13 structure, JT=128) ----------------
__global__ __launch_bounds__(256, 2) void k_knn(const float* __restrict__ xn,
                      const float* __restrict__ sq,
                      float* __restrict__ pd, int* __restrict__ pi_){
  __shared__ float xjL[JT*64];
  __shared__ float sqL[JT];
  int bx = blockIdx.x;
  if (bx >= 512) return;
  int b     = bx >> 8;
  int ib    = (bx >> 4) & 15;
  int split = bx & 15;
  int tid = threadIdx.x;
  const float* xb = xn + (size_t)b*NN*64;
  const float* sqb = sq + (size_t)b*NN;
  int i = ib*256 + tid;
  float4 xi[16];
  {
    const float4* p = (const float4*)(xb + (size_t)i*64);
    #pragma unroll
    for (int q=0;q<16;q++) xi[q] = p[q];
  }
  #pragma unroll
  for (int q=0;q<16;q++){
    asm volatile("" : "+v"(xi[q].x), "+v"(xi[q].y), "+v"(xi[q].z), "+v"(xi[q].w));
  }
  float sqi = sqb[i];
  float bd[9]; int bi[9];
  #pragma unroll
  for (int q=0;q<9;q++){ bd[q]=INFINITY; bi[q]=0x7fffffff; }
  float wd=INFINITY; int wi=0x7fffffff;
  int jbase = split*CHUNK;
  for (int tile=0; tile<CHUNK/JT; tile++){
    int jt = jbase + tile*JT;
    __syncthreads();
    {
      const float4* src = (const float4*)(xb + (size_t)jt*64);
      float4* dst = (float4*)xjL;
      #pragma unroll
      for (int u=0; u<JT*16/256; u++) dst[u*256 + tid] = src[u*256 + tid];
      if (tid < JT) sqL[tid] = sqb[jt + tid];
    }
    __syncthreads();
    for (int jj=0; jj<JT; jj++){
      const float4* xj = (const float4*)(xjL + jj*64);
      float a0=0.f,a1=0.f,a2=0.f,a3=0.f;
      #pragma unroll
      for (int q=0;q<16;q++){
        float4 v = xj[q];
        a0 = fmaf(xi[q].x, v.x, a0);
        a1 = fmaf(xi[q].y, v.y, a1);
        a2 = fmaf(xi[q].z, v.z, a2);
        a3 = fmaf(xi[q].w, v.w, a3);
      }
      float dot = (a0+a1)+(a2+a3);
      int j = jt + jj;
      float d = sqi + sqL[jj] - 2.f*dot;
      topk_insert(d, j, bd, bi, wd, wi);
    }
  }
  size_t base = (((size_t)(b*NN + i))*SPLIT + split)*9;
  #pragma unroll
  for (int q=0;q<9;q++){ pd[base+q]=bd[q]; pi_[base+q]=bi[q]; }
}

// ------- edge pass 1: fused merge + edge-GEMM stats; wave-private, barrier-free -----
__global__ __launch_bounds__(256) void k_edge1(const float* __restrict__ h,
                        const float* __restrict__ pd, const int* __restrict__ pi_,
                        const float* __restrict__ Wg, const float* __restrict__ bg,
                        int* __restrict__ idxf, float* __restrict__ part){
  __shared__ float dxAll[4*576];
  __shared__ float xiAll[4*64];
  __shared__ float sSum[512], sSq[512];
  int tid = threadIdx.x, lane = tid & 63, wv = tid >> 6;
  float* dxW = dxAll + wv*576;
  float* xiW = xiAll + wv*64;
  int c0 = lane, c1 = lane + 64;
  float bias0 = bg[c0], bias1 = bg[c1];
  float sm0=0.f, ss0=0.f, sm1=0.f, ss1=0.f;
  for (int u4=0; u4<4; u4++){
    int node = blockIdx.x*16 + wv*4 + u4;
    int b = node >> 12;
    size_t cb = (size_t)node*(SPLIT*9);
    float d0 = pd[cb+lane], d1 = pd[cb+64+lane], d2 = INFINITY;
    int   j0 = pi_[cb+lane], j1 = pi_[cb+64+lane], j2 = 0x7fffffff;
    if (lane < 16){ d2 = pd[cb+128+lane]; j2 = pi_[cb+128+lane]; }
    int kidx[9];
    #pragma unroll
    for (int s=0; s<9; s++){
      float ld = d0; int lj = j0;
      if (d1 < ld || (d1 == ld && j1 < lj)){ ld = d1; lj = j1; }
      if (d2 < ld || (d2 == ld && j2 < lj)){ ld = d2; lj = j2; }
      #pragma unroll
      for (int off=1; off<64; off<<=1){
        float od = __shfl_xor(ld, off, 64);
        int   oj = __shfl_xor(lj, off, 64);
        if (od < ld || (od == ld && oj < lj)){ ld = od; lj = oj; }
      }
      kidx[s] = lj & (NN-1);
      if (lane == 0) idxf[(size_t)node*9 + s] = lj & (NN-1);
      if (j0 == lj){ d0 = INFINITY; j0 = 0x7fffffff; }
      if (j1 == lj){ d1 = INFINITY; j1 = 0x7fffffff; }
      if (j2 == lj){ d2 = INFINITY; j2 = 0x7fffffff; }
    }
    float xi_l = h[(size_t)node*64 + lane];
    xiW[lane] = xi_l;
    #pragma unroll
    for (int k=0; k<9; k++)
      dxW[k*64+lane] = h[((size_t)(b*NN + kidx[k]))*64 + lane] - xi_l;
    float common0 = bias0, common1 = bias1;
    for (int d=0; d<64; d++){
      float xv = xiW[d];
      common0 = fmaf(xv, Wg[d*C2+c0], common0);
      common1 = fmaf(xv, Wg[d*C2+c1], common1);
    }
    float a0[9], a1[9];
    #pragma unroll
    for (int k=0;k<9;k++){ a0[k]=0.f; a1[k]=0.f; }
    for (int d=0; d<64; d++){
      float w0 = Wg[(64+d)*C2+c0], w1 = Wg[(64+d)*C2+c1];
      #pragma unroll
      for (int k=0;k<9;k++){
        float dxv = dxW[k*64+d];
        a0[k] = fmaf(dxv, w0, a0[k]);
        a1[k] = fmaf(dxv, w1, a1[k]);
      }
    }
    #pragma unroll
    for (int k=0;k<9;k++){
      float v0 = common0 + a0[k], v1 = common1 + a1[k];
      sm0 += v0; ss0 += v0*v0; sm1 += v1; ss1 += v1*v1;
    }
  }
  sSum[wv*128+lane] = sm0; sSum[wv*128+64+lane] = sm1;
  sSq [wv*128+lane] = ss0; sSq [wv*128+64+lane] = ss1;
  __syncthreads();
  if (tid < 128){
    float sm = sSum[tid]+sSum[128+tid]+sSum[256+tid]+sSum[384+tid];
    float ss = sSq[tid]+sSq[128+tid]+sSq[256+tid]+sSq[384+tid];
    part[blockIdx.x*256 + tid] = sm;
    part[blockIdx.x*256 + 128 + tid] = ss;
  }
}

// ------- edge pass 2: inline fin (G=512,Cc=128) + recompute + BN + gelu + max ------
__global__ __launch_bounds__(256) void k_edge2(const float* __restrict__ h,
                        const int* __restrict__ idxf,
                        const float* __restrict__ Wg, const float* __restrict__ bg,
                        const float* __restrict__ part, const float* __restrict__ gg,
                        const float* __restrict__ btg, float* __restrict__ gmax){
  __shared__ float dxAll[4*576];
  __shared__ float xiAll[4*64];
  __shared__ float scshL[256];
  __shared__ float s1[256], s2[256];
  int tid = threadIdx.x, lane = tid & 63, wv = tid >> 6;
  {
    int cc = tid & 127, sl = tid >> 7;
    float sm=0.f, ss=0.f;
    #pragma unroll 4
    for (int u=sl*256; u<sl*256+256; u++){ sm += part[u*256+cc]; ss += part[u*256+128+cc]; }
    s1[tid]=sm; s2[tid]=ss;
  }
  __syncthreads();
  if (tid < 128){
    float sm = s1[tid]+s1[128+tid];
    float ss = s2[tid]+s2[128+tid];
    float mean = sm/(float)RG;
    float var = fmaxf(ss/(float)RG - mean*mean, 0.f);
    float sc = gg[tid]*rsqrtf(var+1e-5f);
    scshL[tid] = sc; scshL[128+tid] = btg[tid] - mean*sc;
  }
  __syncthreads();
  float* dxW = dxAll + wv*576;
  float* xiW = xiAll + wv*64;
  int c0 = lane, c1 = lane + 64;
  float bias0 = bg[c0], bias1 = bg[c1];
  float sc0 = scshL[c0], sh0 = scshL[128+c0];
  float sc1 = scshL[c1], sh1 = scshL[128+c1];
  for (int u4=0; u4<4; u4++){
    int node = blockIdx.x*16 + wv*4 + u4;
    int b = node >> 12;
    int kidx[9];
    #pragma unroll
    for (int k=0;k<9;k++) kidx[k] = idxf[(size_t)node*9 + k] & (NN-1);
    float xi_l = h[(size_t)node*64 + lane];
    xiW[lane] = xi_l;
    #pragma unroll
    for (int k=0; k<9; k++)
      dxW[k*64+lane] = h[((size_t)(b*NN + kidx[k]))*64 + lane] - xi_l;
    float common0 = bias0, common1 = bias1;
    for (int d=0; d<64; d++){
      float xv = xiW[d];
      common0 = fmaf(xv, Wg[d*C2+c0], common0);
      common1 = fmaf(xv, Wg[d*C2+c1], common1);
    }
    float a0[9], a1[9];
    #pragma unroll
    for (int k=0;k<9;k++){ a0[k]=0.f; a1[k]=0.f; }
    for (int d=0; d<64; d++){
      float w0 = Wg[(64+d)*C2+c0], w1 = Wg[(64+d)*C2+c1];
      #pragma unroll
      for (int k=0;k<9;k++){
        float dxv = dxW[k*64+d];
        a0[k] = fmaf(dxv, w0, a0[k]);
        a1[k] = fmaf(dxv, w1, a1[k]);
      }
    }
    float m0 = -INFINITY, m1 = -INFINITY;
    #pragma unroll
    for (int k=0;k<9;k++){
      m0 = fmaxf(m0, gelu(fmaf(common0 + a0[k], sc0, sh0)));
      m1 = fmaxf(m1, gelu(fmaf(common1 + a1[k], sc1, sh1)));
    }
    gmax[(size_t)node*C2 + c0] = m0;
    gmax[(size_t)node*C2 + c1] = m1;
  }
}

// ------- inline fin(G=256,Cc=64) + BN2 + residual + FFN1 GEMM + stats --------------
__global__ void k_ffn1_fused(const float* __restrict__ Y2, const float* __restrict__ part,
                             const float* __restrict__ g2, const float* __restrict__ bt2,
                             const float* __restrict__ x0f, float* __restrict__ outt,
                             const float* __restrict__ Wf1, const float* __restrict__ bf1,
                             float* __restrict__ partB){
  __shared__ float scshL[128];
  __shared__ float otL[32*64];
  __shared__ float WL[64*256];
  __shared__ float s1[256], s2[256];
  int tid = threadIdx.x;
  int r0 = blockIdx.x*32;
  {
    const float4* s4 = (const float4*)Wf1; float4* d4 = (float4*)WL;
    #pragma unroll
    for (int u=0; u<16; u++) d4[u*256+tid] = s4[u*256+tid];
  }
  {
    int c = tid & 63, sl = tid >> 6;
    float sm=0.f, ss=0.f;
    #pragma unroll 4
    for (int u=sl*64; u<sl*64+64; u++){ sm += part[u*128+c]; ss += part[u*128+64+c]; }
    s1[tid]=sm; s2[tid]=ss;
  }
  __syncthreads();
  if (tid < 64){
    float sm = s1[tid]+s1[64+tid]+s1[128+tid]+s1[192+tid];
    float ss = s2[tid]+s2[64+tid]+s2[128+tid]+s2[192+tid];
    float mean = sm/(float)R1;
    float var = fmaxf(ss/(float)R1 - mean*mean, 0.f);
    float sc = g2[tid]*rsqrtf(var+1e-5f);
    scshL[tid] = sc; scshL[64+tid] = bt2[tid] - mean*sc;
  }
  __syncthreads();
  for (int p=0; p<8; p++){
    int idx = p*256 + tid;
    int lr = idx >> 6, cc = idx & 63;
    size_t gi = (size_t)(r0+lr)*64 + cc;
    float v = fmaf(Y2[gi], scshL[cc], scshL[64+cc]) + x0f[gi];
    otL[idx] = v; outt[gi] = v;
  }
  __syncthreads();
  float bias = bf1[tid];
  float sm=0.f, ss=0.f;
  for (int lr=0; lr<32; lr++){
    float acc = bias;
    for (int d=0; d<64; d++) acc = fmaf(otL[lr*64+d], WL[d*256+tid], acc);
    sm += acc; ss += acc*acc;
  }
  partB[blockIdx.x*512 + tid] = sm;
  partB[blockIdx.x*512 + 256 + tid] = ss;
}

// ------- inline fin(G=256,Cc=256) + FFN1-recompute + gelu + FFN2 GEMM + stats ------
__global__ void k_ffn2_fused(const float* __restrict__ outt, const float* __restrict__ Wf1,
                             const float* __restrict__ bf1, const float* __restrict__ partB,
                             const float* __restrict__ gf1, const float* __restrict__ btf1,
                             const float* __restrict__ Wf2, const float* __restrict__ bf2,
                             float* __restrict__ Yf2, float* __restrict__ partA){
  __shared__ float scshL[512];
  __shared__ float otL[32*64];
  __shared__ float fLL[32*256];
  __shared__ float s1[256], s2[256];
  int tid = threadIdx.x;
  int r0 = blockIdx.x*32;
  {
    float sm=0.f, ss=0.f;
    #pragma unroll 4
    for (int u=0; u<256; u++){ sm += partB[u*512+tid]; ss += partB[u*512+256+tid]; }
    float mean = sm/(float)R1;
    float var = fmaxf(ss/(float)R1 - mean*mean, 0.f);
    float sc = gf1[tid]*rsqrtf(var+1e-5f);
    scshL[tid] = sc; scshL[256+tid] = btf1[tid] - mean*sc;
  }
  for (int p=0; p<8; p++){
    int idx = p*256 + tid;
    otL[idx] = outt[(size_t)r0*64 + idx];
  }
  __syncthreads();
  float bias = bf1[tid];
  for (int lr=0; lr<32; lr++){
    float acc = bias;
    for (int d=0; d<64; d++) acc = fmaf(otL[lr*64+d], Wf1[d*256+tid], acc);
    float v = fmaf(acc, scshL[tid], scshL[256+tid]);
    fLL[lr*256+tid] = gelu(v);
  }
  __syncthreads();
  int c = tid & 63, rs = tid >> 6;
  float b2z = bf2[c];
  float sm=0.f, ss=0.f;
  for (int it=0; it<8; it++){
    int lr = it*4 + rs;
    float acc = b2z;
    for (int d=0; d<256; d++) acc = fmaf(fLL[lr*256+d], Wf2[d*64+c], acc);
    Yf2[(size_t)(r0+lr)*64 + c] = acc;
    sm += acc; ss += acc*acc;
  }
  s1[tid]=sm; s2[tid]=ss;
  __syncthreads();
  if (tid < 64){
    sm = s1[tid]+s1[64+tid]+s1[128+tid]+s1[192+tid];
    ss = s2[tid]+s2[64+tid]+s2[128+tid]+s2[192+tid];
    partA[blockIdx.x*128 + tid] = sm;
    partA[blockIdx.x*128 + 64 + tid] = ss;
  }
}

// ---------------- inline fin(G=256,Cc=64) + BNf2 + residual -> feats[t] ------------
__global__ void k_final(const float* __restrict__ Yf2, const float* __restrict__ partA,
                        const float* __restrict__ gf2, const float* __restrict__ btf2,
                        const float* __restrict__ outt, float* __restrict__ feat){
  __shared__ float scshL[128];
  __shared__ float s1[256], s2[256];
  int tid = threadIdx.x;
  {
    int c = tid & 63, sl = tid >> 6;
    float sm=0.f, ss=0.f;
    #pragma unroll 4
    for (int u=sl*64; u<sl*64+64; u++){ sm += partA[u*128+c]; ss += partA[u*128+64+c]; }
    s1[tid]=sm; s2[tid]=ss;
  }
  __syncthreads();
  if (tid < 64){
    float sm = s1[tid]+s1[64+tid]+s1[128+tid]+s1[192+tid];
    float ss = s2[tid]+s2[64+tid]+s2[128+tid]+s2[192+tid];
    float mean = sm/(float)R1;
    float var = fmaxf(ss/(float)R1 - mean*mean, 0.f);
    float sc = gf2[tid]*rsqrtf(var+1e-5f);
    scshL[tid] = sc; scshL[64+tid] = btf2[tid] - mean*sc;
  }
  __syncthreads();
  size_t base = (size_t)blockIdx.x*2048;
  for (int p=0; p<8; p++){
    size_t idx = base + p*256 + tid;
    int cc = idx & 63;
    feat[idx] = fmaf(Yf2[idx], scshL[cc], scshL[64+cc]) + outt[idx];
  }
}

// ---------------- alpha-mix + transpose -> output (T,B,C,N) fp32 ----------------
__global__ void k_mix(const float* __restrict__ f0, const float* __restrict__ f1,
                      const float* __restrict__ alpha, float* __restrict__ outv){
  int idx = blockIdx.x*256 + threadIdx.x;
  if (idx >= TT*BB*CCH*NN) return;
  int n = idx & (NN-1);
  int c = (idx >> 12) & 63;
  int b = (idx >> 18) & 1;
  int i = idx >> 19;
  float a0 = alpha[i*TT + 0];
  float a1 = alpha[i*TT + 1];
  size_t fi = ((size_t)(b*NN + n))*64 + c;
  outv[idx] = a0*f0[fi] + a1*f1[fi];
}

extern "C" void kernel_launch(void* const* d_in, const int* in_sizes, int n_in,
                              void* d_out, int out_size, void* d_ws, size_t ws_size,
                              hipStream_t stream){
  float* outp = (float*)d_out;

  static const int expect[22] = {
    524288, 8192, 128, 128, 128, 32768, 256, 256, 256, 16384, 128, 128, 128,
    32768, 512, 512, 512, 32768, 128, 128, 128, 4
  };
  bool ok = (n_in == 22) && (out_size == TT*BB*CCH*NN) &&
            (ws_size >= WS_TOTAL*sizeof(float));
  if (ok){
    for (int i=0;i<22;i++) if (in_sizes[i] != expect[i]) { ok = false; break; }
  }
  if (!ok){
    k_zero<<<(out_size+255)/256,256,0,stream>>>(outp, out_size);
    return;
  }

  const float* x   = (const float*)d_in[0];
  const float* W1  = (const float*)d_in[1];
  const float* b1  = (const float*)d_in[2];
  const float* g1  = (const float*)d_in[3];
  const float* bt1 = (const float*)d_in[4];
  const float* Wg  = (const float*)d_in[5];
  const float* bg  = (const float*)d_in[6];
  const float* gg  = (const float*)d_in[7];
  const float* btg = (const float*)d_in[8];
  const float* W2  = (const float*)d_in[9];
  const float* b2v = (const float*)d_in[10];
  const float* g2  = (const float*)d_in[11];
  const float* bt2 = (const float*)d_in[12];
  const float* Wf1 = (const float*)d_in[13];
  const float* bf1v= (const float*)d_in[14];
  const float* gf1 = (const float*)d_in[15];
  const float* btf1= (const float*)d_in[16];
  const float* Wf2 = (const float*)d_in[17];
  const float* bf2v= (const float*)d_in[18];
  const float* gf2 = (const float*)d_in[19];
  const float* btf2= (const float*)d_in[20];
  const float* alpha=(const float*)d_in[21];
  float* ws = (float*)d_ws;

  float* x0f  = ws + 0;
  float* hbuf = ws + 524288;
  float* xnb  = ws + 1048576;
  float* sqb  = ws + 1572864;
  float* partA= ws + 1581056;
  int*   idxf = (int*)(ws + 1712640);
  float* f0   = ws + 1786368;
  float* f1b  = ws + 2310656;
  float* Rbig = ws + 2834944;
  float* pdist = Rbig;
  int*   pidx  = (int*)(Rbig + (size_t)R1*SPLIT*9);
  float* gmaxb = Rbig;
  float* outt  = Rbig + 1048576;
  float* Y2    = Rbig + 1572864;
  float* partB = Rbig + 2097152;
  float* Yf2   = Rbig;

  k_transpose<<<2048,256,0,stream>>>(x, x0f);
  float* feats[2] = {f0, f1b};
  for (int t=0; t<TT; t++){
    k_gemm1_stats<<<256,256,0,stream>>>(x0f, W1 + t*CCH*CCH, b1 + t*64, hbuf, partA);
    k_applynorm3<<<256,256,0,stream>>>(hbuf, partA, g1 + t*64, bt1 + t*64, xnb, sqb);
    k_knn<<<512,256,0,stream>>>(xnb, sqb, pdist, pidx);
    k_edge1<<<512,256,0,stream>>>(hbuf, pdist, pidx, Wg + t*C2*C2, bg + t*C2, idxf, partA);
    k_edge2<<<512,256,0,stream>>>(hbuf, idxf, Wg + t*C2*C2, bg + t*C2,
                                  partA, gg + t*C2, btg + t*C2, gmaxb);
    k_gemm2_stats<<<256,256,0,stream>>>(gmaxb, W2 + t*C2*CCH, b2v + t*64, Y2, partA);
    k_ffn1_fused<<<256,256,0,stream>>>(Y2, partA, g2 + t*64, bt2 + t*64, x0f, outt,
                                       Wf1 + t*CCH*C4, bf1v + t*C4, partB);
    k_ffn2_fused<<<256,256,0,stream>>>(outt, Wf1 + t*CCH*C4, bf1v + t*C4, partB,
                                       gf1 + t*C4, btf1 + t*C4,
                                       Wf2 + t*C4*CCH, bf2v + t*64, Yf2, partA);
    k_final<<<256,256,0,stream>>>(Yf2, partA, gf2 + t*64, btf2 + t*64, outt, feats[t]);
  }
  k_mix<<<4096,256,0,stream>>>(f0, f1b, alpha, outp);
}

// Round 16
// 1363.679 us; speedup vs baseline: 1.3027x; 1.1110x over previous
//
#include <hip/hip_runtime.h>
#include <math.h>

#define BB 2
#define CCH 64
#define NN 4096
#define KK 9
#define TT 2
#define C2 128
#define C4 256
#define R1 (BB*NN)        /* 8192  */
#define RG (BB*NN*KK)     /* 73728 */
#define SPLIT 16
#define CHUNK (NN/SPLIT)  /* 256 */
#define JT 128            /* j-tile rows staged in LDS */

#define WS_TOTAL 5194240ull
#define WS_BIG   (5194240ull + 9437184ull)   /* + Yg (RG*C2) */

__device__ __forceinline__ float gelu(float v){ return 0.5f*v*(1.f + erff(v*0.70710678118654752f)); }

__global__ void k_zero(float* __restrict__ o, int n){
  int i = blockIdx.x*256 + threadIdx.x;
  if (i < n) o[i] = 0.f;
}

// ---------------- transpose x (B,C,N) -> x0f (B,N,C) ----------------
__global__ void k_transpose(const float* __restrict__ x, float* __restrict__ x0f){
  int idx = blockIdx.x*256 + threadIdx.x;
  if (idx >= BB*NN*CCH) return;
  int c = idx & (CCH-1);
  int n = (idx >> 6) & (NN-1);
  int b = idx >> 18;
  x0f[idx] = x[(size_t)(b*CCH + c)*NN + n];
}

// ---------------- GEMM1 (64->64) + stats: 256 blocks x 32 rows ----------------
__global__ void k_gemm1_stats(const float* __restrict__ X, const float* __restrict__ W,
                              const float* __restrict__ bias, float* __restrict__ Y,
                              float* __restrict__ part){
  __shared__ float WL[64*64];
  __shared__ float xL[32*64];
  __shared__ float s1[256], s2[256];
  int tid = threadIdx.x;
  int r0 = blockIdx.x*32;
  {
    const float4* ws4 = (const float4*)W;
    float4* wd4 = (float4*)WL;
    #pragma unroll
    for (int u=0; u<4; u++) wd4[u*256+tid] = ws4[u*256+tid];
    const float4* xs4 = (const float4*)(X + (size_t)r0*64);
    float4* xd4 = (float4*)xL;
    #pragma unroll
    for (int u=0; u<2; u++) xd4[u*256+tid] = xs4[u*256+tid];
  }
  __syncthreads();
  int c = tid & 63, rs = tid >> 6;
  float bz = bias[c];
  float sm=0.f, ss=0.f;
  for (int it=0; it<8; it++){
    int lr = it*4 + rs;
    float acc = bz;
    for (int d=0; d<64; d++) acc = fmaf(xL[lr*64+d], WL[d*64+c], acc);
    Y[(size_t)(r0+lr)*64 + c] = acc;
    sm += acc; ss += acc*acc;
  }
  s1[tid]=sm; s2[tid]=ss;
  __syncthreads();
  if (tid < 64){
    sm = s1[tid]+s1[64+tid]+s1[128+tid]+s1[192+tid];
    ss = s2[tid]+s2[64+tid]+s2[128+tid]+s2[192+tid];
    part[blockIdx.x*128 + tid] = sm;
    part[blockIdx.x*128 + 64 + tid] = ss;
  }
}

// ---------------- GEMM2 (128->64) + stats: 256 blocks x 32 rows ----------------
__global__ void k_gemm2_stats(const float* __restrict__ X, const float* __restrict__ W,
                              const float* __restrict__ bias, float* __restrict__ Y,
                              float* __restrict__ part){
  __shared__ float WL[128*64];
  __shared__ float xL[32*128];
  __shared__ float s1[256], s2[256];
  int tid = threadIdx.x;
  int r0 = blockIdx.x*32;
  {
    const float4* ws4 = (const float4*)W;
    float4* wd4 = (float4*)WL;
    #pragma unroll
    for (int u=0; u<8; u++) wd4[u*256+tid] = ws4[u*256+tid];
    const float4* xs4 = (const float4*)(X + (size_t)r0*128);
    float4* xd4 = (float4*)xL;
    #pragma unroll
    for (int u=0; u<4; u++) xd4[u*256+tid] = xs4[u*256+tid];
  }
  __syncthreads();
  int c = tid & 63, rs = tid >> 6;
  float bz = bias[c];
  float sm=0.f, ss=0.f;
  for (int it=0; it<8; it++){
    int lr = it*4 + rs;
    float acc = bz;
    for (int d=0; d<128; d++) acc = fmaf(xL[lr*128+d], WL[d*64+c], acc);
    Y[(size_t)(r0+lr)*64 + c] = acc;
    sm += acc; ss += acc*acc;
  }
  s1[tid]=sm; s2[tid]=ss;
  __syncthreads();
  if (tid < 64){
    sm = s1[tid]+s1[64+tid]+s1[128+tid]+s1[192+tid];
    ss = s2[tid]+s2[64+tid]+s2[128+tid]+s2[192+tid];
    part[blockIdx.x*128 + tid] = sm;
    part[blockIdx.x*128 + 64 + tid] = ss;
  }
}

// ---------------- inline fin (G=256, Cc=64) + BN apply + row-normalize ------------
__global__ void k_applynorm3(float* __restrict__ h, const float* __restrict__ part,
                             const float* __restrict__ g, const float* __restrict__ bt,
                             float* __restrict__ xn, float* __restrict__ sq){
  __shared__ float scshL[128];
  __shared__ float s1[256], s2[256];
  int tid = threadIdx.x;
  {
    int c = tid & 63, sl = tid >> 6;
    float sm=0.f, ss=0.f;
    #pragma unroll 4
    for (int u=sl*64; u<sl*64+64; u++){ sm += part[u*128+c]; ss += part[u*128+64+c]; }
    s1[tid]=sm; s2[tid]=ss;
  }
  __syncthreads();
  if (tid < 64){
    float sm = s1[tid]+s1[64+tid]+s1[128+tid]+s1[192+tid];
    float ss = s2[tid]+s2[64+tid]+s2[128+tid]+s2[192+tid];
    float mean = sm/(float)R1;
    float var = fmaxf(ss/(float)R1 - mean*mean, 0.f);
    float sc = g[tid]*rsqrtf(var+1e-5f);
    scshL[tid] = sc; scshL[64+tid] = bt[tid] - mean*sc;
  }
  __syncthreads();
  int lane = tid & 63, w = tid >> 6;
  int r0 = blockIdx.x*32;
  for (int it=0; it<8; it++){
    int r = r0 + w*8 + it;
    float v = fmaf(h[(size_t)r*64+lane], scshL[lane], scshL[64+lane]);
    h[(size_t)r*64+lane] = v;
    float s2v = v*v;
    #pragma unroll
    for (int off=32; off; off>>=1) s2v += __shfl_xor(s2v, off, 64);
    float den = fmaxf(sqrtf(s2v), 1e-12f);
    float xv = v/den;
    xn[(size_t)r*64+lane] = xv;
    float t2 = xv*xv;
    #pragma unroll
    for (int off=32; off; off>>=1) t2 += __shfl_xor(t2, off, 64);
    if (lane==0) sq[r] = t2;
  }
}

// ---------------- top-9 streaming insert (strict <) ----------------
__device__ __forceinline__ void topk_insert(float d, int j, float* bd, int* bi,
                                            float& wd, int& wi){
  if (d < wd){
    bool done=false;
    #pragma unroll
    for (int q=0;q<9;q++){
      if (!done && bd[q]==wd && bi[q]==wi){ bd[q]=d; bi[q]=j; done=true; }
    }
    wd = bd[0]; wi = bi[0];
    #pragma unroll
    for (int q=1;q<9;q++){
      if (bd[q] > wd || (bd[q]==wd && bi[q] > wi)){ wd=bd[q]; wi=bi[q]; }
    }
  }
}

// ---------------- KNN: 1 i-row/thread (R13 structure, JT=128) ----------------
__global__ __launch_bounds__(256, 2) void k_knn(const float* __restrict__ xn,
                      const float* __restrict__ sq,
                      float* __restrict__ pd, int* __restrict__ pi_){
  __shared__ float xjL[JT*64];
  __shared__ float sqL[JT];
  int bx = blockIdx.x;
  int b     = bx >> 8;
  int ib    = (bx >> 4) & 15;
  int split = bx & 15;
  int tid = threadIdx.x;
  const float* xb = xn + (size_t)b*NN*64;
  const float* sqb = sq + (size_t)b*NN;
  int i = ib*256 + tid;
  float4 xi[16];
  {
    const float4* p = (const float4*)(xb + (size_t)i*64);
    #pragma unroll
    for (int q=0;q<16;q++) xi[q] = p[q];
  }
  #pragma unroll
  for (int q=0;q<16;q++){
    asm volatile("" : "+v"(xi[q].x), "+v"(xi[q].y), "+v"(xi[q].z), "+v"(xi[q].w));
  }
  float sqi = sqb[i];
  float bd[9]; int bi[9];
  #pragma unroll
  for (int q=0;q<9;q++){ bd[q]=INFINITY; bi[q]=0x7fffffff; }
  float wd=INFINITY; int wi=0x7fffffff;
  int jbase = split*CHUNK;
  for (int tile=0; tile<CHUNK/JT; tile++){
    int jt = jbase + tile*JT;
    __syncthreads();
    {
      const float4* src = (const float4*)(xb + (size_t)jt*64);
      float4* dst = (float4*)xjL;
      #pragma unroll
      for (int u=0; u<JT*16/256; u++) dst[u*256 + tid] = src[u*256 + tid];
      if (tid < JT) sqL[tid] = sqb[jt + tid];
    }
    __syncthreads();
    for (int jj=0; jj<JT; jj++){
      const float4* xj = (const float4*)(xjL + jj*64);
      float a0=0.f,a1=0.f,a2=0.f,a3=0.f;
      #pragma unroll
      for (int q=0;q<16;q++){
        float4 v = xj[q];
        a0 = fmaf(xi[q].x, v.x, a0);
        a1 = fmaf(xi[q].y, v.y, a1);
        a2 = fmaf(xi[q].z, v.z, a2);
        a3 = fmaf(xi[q].w, v.w, a3);
      }
      float dot = (a0+a1)+(a2+a3);
      int j = jt + jj;
      float d = sqi + sqL[jj] - 2.f*dot;
      topk_insert(d, j, bd, bi, wd, wi);
    }
  }
  size_t base = (((size_t)(b*NN + i))*SPLIT + split)*9;
  #pragma unroll
  for (int q=0;q<9;q++){ pd[base+q]=bd[q]; pi_[base+q]=bi[q]; }
}

// ------- edge pass 1: fused merge + edge-GEMM stats (+Yg store when bigws) ---------
__global__ __launch_bounds__(256) void k_edge1(const float* __restrict__ h,
                        const float* __restrict__ pd, const int* __restrict__ pi_,
                        const float* __restrict__ Wg, const float* __restrict__ bg,
                        int* __restrict__ idxf, float* __restrict__ part,
                        float* __restrict__ Yg, int storeYg){
  __shared__ float dxAll[4*576];
  __shared__ float xiAll[4*64];
  __shared__ float sSum[512], sSq[512];
  int tid = threadIdx.x, lane = tid & 63, wv = tid >> 6;
  float* dxW = dxAll + wv*576;
  float* xiW = xiAll + wv*64;
  int c0 = lane, c1 = lane + 64;
  float bias0 = bg[c0], bias1 = bg[c1];
  float sm0=0.f, ss0=0.f, sm1=0.f, ss1=0.f;
  for (int u4=0; u4<4; u4++){
    int node = blockIdx.x*16 + wv*4 + u4;
    int b = node >> 12;
    size_t cb = (size_t)node*(SPLIT*9);
    float d0 = pd[cb+lane], d1 = pd[cb+64+lane], d2 = INFINITY;
    int   j0 = pi_[cb+lane], j1 = pi_[cb+64+lane], j2 = 0x7fffffff;
    if (lane < 16){ d2 = pd[cb+128+lane]; j2 = pi_[cb+128+lane]; }
    int kidx[9];
    #pragma unroll
    for (int s=0; s<9; s++){
      float ld = d0; int lj = j0;
      if (d1 < ld || (d1 == ld && j1 < lj)){ ld = d1; lj = j1; }
      if (d2 < ld || (d2 == ld && j2 < lj)){ ld = d2; lj = j2; }
      #pragma unroll
      for (int off=1; off<64; off<<=1){
        float od = __shfl_xor(ld, off, 64);
        int   oj = __shfl_xor(lj, off, 64);
        if (od < ld || (od == ld && oj < lj)){ ld = od; lj = oj; }
      }
      kidx[s] = lj & (NN-1);
      if (lane == 0) idxf[(size_t)node*9 + s] = lj & (NN-1);
      if (j0 == lj){ d0 = INFINITY; j0 = 0x7fffffff; }
      if (j1 == lj){ d1 = INFINITY; j1 = 0x7fffffff; }
      if (j2 == lj){ d2 = INFINITY; j2 = 0x7fffffff; }
    }
    float xi_l = h[(size_t)node*64 + lane];
    xiW[lane] = xi_l;
    #pragma unroll
    for (int k=0; k<9; k++)
      dxW[k*64+lane] = h[((size_t)(b*NN + kidx[k]))*64 + lane] - xi_l;
    float common0 = bias0, common1 = bias1;
    for (int d=0; d<64; d++){
      float xv = xiW[d];
      common0 = fmaf(xv, Wg[d*C2+c0], common0);
      common1 = fmaf(xv, Wg[d*C2+c1], common1);
    }
    float a0[9], a1[9];
    #pragma unroll
    for (int k=0;k<9;k++){ a0[k]=0.f; a1[k]=0.f; }
    for (int d=0; d<64; d++){
      float w0 = Wg[(64+d)*C2+c0], w1 = Wg[(64+d)*C2+c1];
      #pragma unroll
      for (int k=0;k<9;k++){
        float dxv = dxW[k*64+d];
        a0[k] = fmaf(dxv, w0, a0[k]);
        a1[k] = fmaf(dxv, w1, a1[k]);
      }
    }
    #pragma unroll
    for (int k=0;k<9;k++){
      float v0 = common0 + a0[k], v1 = common1 + a1[k];
      sm0 += v0; ss0 += v0*v0; sm1 += v1; ss1 += v1*v1;
      if (storeYg){
        size_t yb = ((size_t)node*9 + k)*C2;
        Yg[yb + c0] = v0;
        Yg[yb + c1] = v1;
      }
    }
  }
  sSum[wv*128+lane] = sm0; sSum[wv*128+64+lane] = sm1;
  sSq [wv*128+lane] = ss0; sSq [wv*128+64+lane] = ss1;
  __syncthreads();
  if (tid < 128){
    float sm = sSum[tid]+sSum[128+tid]+sSum[256+tid]+sSum[384+tid];
    float ss = sSq[tid]+sSq[128+tid]+sSq[256+tid]+sSq[384+tid];
    part[blockIdx.x*256 + tid] = sm;
    part[blockIdx.x*256 + 128 + tid] = ss;
  }
}

// ------- edge pass 2 (materialized): inline fin + BN + gelu + max over Yg ---------
__global__ __launch_bounds__(256) void k_edge2m(const float* __restrict__ Yg,
                        const float* __restrict__ part, const float* __restrict__ gg,
                        const float* __restrict__ btg, float* __restrict__ gmax){
  __shared__ float scshL[256];
  __shared__ float s1[256], s2[256];
  int tid = threadIdx.x;
  {
    int cc = tid & 127, sl = tid >> 7;
    float sm=0.f, ss=0.f;
    #pragma unroll 4
    for (int u=sl*256; u<sl*256+256; u++){ sm += part[u*256+cc]; ss += part[u*256+128+cc]; }
    s1[tid]=sm; s2[tid]=ss;
  }
  __syncthreads();
  if (tid < 128){
    float sm = s1[tid]+s1[128+tid];
    float ss = s2[tid]+s2[128+tid];
    float mean = sm/(float)RG;
    float var = fmaxf(ss/(float)RG - mean*mean, 0.f);
    float sc = gg[tid]*rsqrtf(var+1e-5f);
    scshL[tid] = sc; scshL[128+tid] = btg[tid] - mean*sc;
  }
  __syncthreads();
  // 8192 nodes x 128 cols over 512 blocks x 256 threads x 8 items
  size_t base = (size_t)blockIdx.x*2048;
  for (int p=0; p<8; p++){
    size_t idx = base + p*256 + tid;
    int c = idx & 127;
    size_t node = idx >> 7;
    float sc = scshL[c], sh = scshL[128+c];
    size_t yb = node*9*C2 + c;
    float m = -INFINITY;
    #pragma unroll
    for (int k=0;k<9;k++){
      m = fmaxf(m, gelu(fmaf(Yg[yb + (size_t)k*C2], sc, sh)));
    }
    gmax[idx] = m;
  }
}

// ------- edge pass 2 (fallback): inline fin + recompute + BN + gelu + max ---------
__global__ __launch_bounds__(256) void k_edge2(const float* __restrict__ h,
                        const int* __restrict__ idxf,
                        const float* __restrict__ Wg, const float* __restrict__ bg,
                        const float* __restrict__ part, const float* __restrict__ gg,
                        const float* __restrict__ btg, float* __restrict__ gmax){
  __shared__ float dxAll[4*576];
  __shared__ float xiAll[4*64];
  __shared__ float scshL[256];
  __shared__ float s1[256], s2[256];
  int tid = threadIdx.x, lane = tid & 63, wv = tid >> 6;
  {
    int cc = tid & 127, sl = tid >> 7;
    float sm=0.f, ss=0.f;
    #pragma unroll 4
    for (int u=sl*256; u<sl*256+256; u++){ sm += part[u*256+cc]; ss += part[u*256+128+cc]; }
    s1[tid]=sm; s2[tid]=ss;
  }
  __syncthreads();
  if (tid < 128){
    float sm = s1[tid]+s1[128+tid];
    float ss = s2[tid]+s2[128+tid];
    float mean = sm/(float)RG;
    float var = fmaxf(ss/(float)RG - mean*mean, 0.f);
    float sc = gg[tid]*rsqrtf(var+1e-5f);
    scshL[tid] = sc; scshL[128+tid] = btg[tid] - mean*sc;
  }
  __syncthreads();
  float* dxW = dxAll + wv*576;
  float* xiW = xiAll + wv*64;
  int c0 = lane, c1 = lane + 64;
  float bias0 = bg[c0], bias1 = bg[c1];
  float sc0 = scshL[c0], sh0 = scshL[128+c0];
  float sc1 = scshL[c1], sh1 = scshL[128+c1];
  for (int u4=0; u4<4; u4++){
    int node = blockIdx.x*16 + wv*4 + u4;
    int b = node >> 12;
    int kidx[9];
    #pragma unroll
    for (int k=0;k<9;k++) kidx[k] = idxf[(size_t)node*9 + k] & (NN-1);
    float xi_l = h[(size_t)node*64 + lane];
    xiW[lane] = xi_l;
    #pragma unroll
    for (int k=0; k<9; k++)
      dxW[k*64+lane] = h[((size_t)(b*NN + kidx[k]))*64 + lane] - xi_l;
    float common0 = bias0, common1 = bias1;
    for (int d=0; d<64; d++){
      float xv = xiW[d];
      common0 = fmaf(xv, Wg[d*C2+c0], common0);
      common1 = fmaf(xv, Wg[d*C2+c1], common1);
    }
    float a0[9], a1[9];
    #pragma unroll
    for (int k=0;k<9;k++){ a0[k]=0.f; a1[k]=0.f; }
    for (int d=0; d<64; d++){
      float w0 = Wg[(64+d)*C2+c0], w1 = Wg[(64+d)*C2+c1];
      #pragma unroll
      for (int k=0;k<9;k++){
        float dxv = dxW[k*64+d];
        a0[k] = fmaf(dxv, w0, a0[k]);
        a1[k] = fmaf(dxv, w1, a1[k]);
      }
    }
    float m0 = -INFINITY, m1 = -INFINITY;
    #pragma unroll
    for (int k=0;k<9;k++){
      m0 = fmaxf(m0, gelu(fmaf(common0 + a0[k], sc0, sh0)));
      m1 = fmaxf(m1, gelu(fmaf(common1 + a1[k], sc1, sh1)));
    }
    gmax[(size_t)node*C2 + c0] = m0;
    gmax[(size_t)node*C2 + c1] = m1;
  }
}

// ------- inline fin(G=256,Cc=64) + BN2 + residual + FFN1 GEMM + stats --------------
__global__ void k_ffn1_fused(const float* __restrict__ Y2, const float* __restrict__ part,
                             const float* __restrict__ g2, const float* __restrict__ bt2,
                             const float* __restrict__ x0f, float* __restrict__ outt,
                             const float* __restrict__ Wf1, const float* __restrict__ bf1,
                             float* __restrict__ partB){
  __shared__ float scshL[128];
  __shared__ float otL[32*64];
  __shared__ float WL[64*256];
  __shared__ float s1[256], s2[256];
  int tid = threadIdx.x;
  int r0 = blockIdx.x*32;
  {
    const float4* s4 = (const float4*)Wf1; float4* d4 = (float4*)WL;
    #pragma unroll
    for (int u=0; u<16; u++) d4[u*256+tid] = s4[u*256+tid];
  }
  {
    int c = tid & 63, sl = tid >> 6;
    float sm=0.f, ss=0.f;
    #pragma unroll 4
    for (int u=sl*64; u<sl*64+64; u++){ sm += part[u*128+c]; ss += part[u*128+64+c]; }
    s1[tid]=sm; s2[tid]=ss;
  }
  __syncthreads();
  if (tid < 64){
    float sm = s1[tid]+s1[64+tid]+s1[128+tid]+s1[192+tid];
    float ss = s2[tid]+s2[64+tid]+s2[128+tid]+s2[192+tid];
    float mean = sm/(float)R1;
    float var = fmaxf(ss/(float)R1 - mean*mean, 0.f);
    float sc = g2[tid]*rsqrtf(var+1e-5f);
    scshL[tid] = sc; scshL[64+tid] = bt2[tid] - mean*sc;
  }
  __syncthreads();
  for (int p=0; p<8; p++){
    int idx = p*256 + tid;
    int lr = idx >> 6, cc = idx & 63;
    size_t gi = (size_t)(r0+lr)*64 + cc;
    float v = fmaf(Y2[gi], scshL[cc], scshL[64+cc]) + x0f[gi];
    otL[idx] = v; outt[gi] = v;
  }
  __syncthreads();
  float bias = bf1[tid];
  float sm=0.f, ss=0.f;
  for (int lr=0; lr<32; lr++){
    float acc = bias;
    for (int d=0; d<64; d++) acc = fmaf(otL[lr*64+d], WL[d*256+tid], acc);
    sm += acc; ss += acc*acc;
  }
  partB[blockIdx.x*512 + tid] = sm;
  partB[blockIdx.x*512 + 256 + tid] = ss;
}

// ------- inline fin(G=256,Cc=256) + FFN1-recompute + gelu + FFN2 GEMM + stats ------
__global__ void k_ffn2_fused(const float* __restrict__ outt, const float* __restrict__ Wf1,
                             const float* __restrict__ bf1, const float* __restrict__ partB,
                             const float* __restrict__ gf1, const float* __restrict__ btf1,
                             const float* __restrict__ Wf2, const float* __restrict__ bf2,
                             float* __restrict__ Yf2, float* __restrict__ partA){
  __shared__ float scshL[512];
  __shared__ float otL[32*64];
  __shared__ float fLL[32*256];
  __shared__ float s1[256], s2[256];
  int tid = threadIdx.x;
  int r0 = blockIdx.x*32;
  {
    float sm=0.f, ss=0.f;
    #pragma unroll 4
    for (int u=0; u<256; u++){ sm += partB[u*512+tid]; ss += partB[u*512+256+tid]; }
    float mean = sm/(float)R1;
    float var = fmaxf(ss/(float)R1 - mean*mean, 0.f);
    float sc = gf1[tid]*rsqrtf(var+1e-5f);
    scshL[tid] = sc; scshL[256+tid] = btf1[tid] - mean*sc;
  }
  for (int p=0; p<8; p++){
    int idx = p*256 + tid;
    otL[idx] = outt[(size_t)r0*64 + idx];
  }
  __syncthreads();
  float bias = bf1[tid];
  for (int lr=0; lr<32; lr++){
    float acc = bias;
    for (int d=0; d<64; d++) acc = fmaf(otL[lr*64+d], Wf1[d*256+tid], acc);
    float v = fmaf(acc, scshL[tid], scshL[256+tid]);
    fLL[lr*256+tid] = gelu(v);
  }
  __syncthreads();
  int c = tid & 63, rs = tid >> 6;
  float b2z = bf2[c];
  float sm=0.f, ss=0.f;
  for (int it=0; it<8; it++){
    int lr = it*4 + rs;
    float acc = b2z;
    for (int d=0; d<256; d++) acc = fmaf(fLL[lr*256+d], Wf2[d*64+c], acc);
    Yf2[(size_t)(r0+lr)*64 + c] = acc;
    sm += acc; ss += acc*acc;
  }
  s1[tid]=sm; s2[tid]=ss;
  __syncthreads();
  if (tid < 64){
    sm = s1[tid]+s1[64+tid]+s1[128+tid]+s1[192+tid];
    ss = s2[tid]+s2[64+tid]+s2[128+tid]+s2[192+tid];
    partA[blockIdx.x*128 + tid] = sm;
    partA[blockIdx.x*128 + 64 + tid] = ss;
  }
}

// ---------------- inline fin(G=256,Cc=64) + BNf2 + residual -> feats[t] ------------
__global__ void k_final(const float* __restrict__ Yf2, const float* __restrict__ partA,
                        const float* __restrict__ gf2, const float* __restrict__ btf2,
                        const float* __restrict__ outt, float* __restrict__ feat){
  __shared__ float scshL[128];
  __shared__ float s1[256], s2[256];
  int tid = threadIdx.x;
  {
    int c = tid & 63, sl = tid >> 6;
    float sm=0.f, ss=0.f;
    #pragma unroll 4
    for (int u=sl*64; u<sl*64+64; u++){ sm += partA[u*128+c]; ss += partA[u*128+64+c]; }
    s1[tid]=sm; s2[tid]=ss;
  }
  __syncthreads();
  if (tid < 64){
    float sm = s1[tid]+s1[64+tid]+s1[128+tid]+s1[192+tid];
    float ss = s2[tid]+s2[64+tid]+s2[128+tid]+s2[192+tid];
    float mean = sm/(float)R1;
    float var = fmaxf(ss/(float)R1 - mean*mean, 0.f);
    float sc = gf2[tid]*rsqrtf(var+1e-5f);
    scshL[tid] = sc; scshL[64+tid] = btf2[tid] - mean*sc;
  }
  __syncthreads();
  size_t base = (size_t)blockIdx.x*2048;
  for (int p=0; p<8; p++){
    size_t idx = base + p*256 + tid;
    int cc = idx & 63;
    feat[idx] = fmaf(Yf2[idx], scshL[cc], scshL[64+cc]) + outt[idx];
  }
}

// ---------------- alpha-mix + transpose -> output (T,B,C,N) fp32 ----------------
__global__ void k_mix(const float* __restrict__ f0, const float* __restrict__ f1,
                      const float* __restrict__ alpha, float* __restrict__ outv){
  int idx = blockIdx.x*256 + threadIdx.x;
  if (idx >= TT*BB*CCH*NN) return;
  int n = idx & (NN-1);
  int c = (idx >> 12) & 63;
  int b = (idx >> 18) & 1;
  int i = idx >> 19;
  float a0 = alpha[i*TT + 0];
  float a1 = alpha[i*TT + 1];
  size_t fi = ((size_t)(b*NN + n))*64 + c;
  outv[idx] = a0*f0[fi] + a1*f1[fi];
}

extern "C" void kernel_launch(void* const* d_in, const int* in_sizes, int n_in,
                              void* d_out, int out_size, void* d_ws, size_t ws_size,
                              hipStream_t stream){
  float* outp = (float*)d_out;

  static const int expect[22] = {
    524288, 8192, 128, 128, 128, 32768, 256, 256, 256, 16384, 128, 128, 128,
    32768, 512, 512, 512, 32768, 128, 128, 128, 4
  };
  bool ok = (n_in == 22) && (out_size == TT*BB*CCH*NN) &&
            (ws_size >= WS_TOTAL*sizeof(float));
  if (ok){
    for (int i=0;i<22;i++) if (in_sizes[i] != expect[i]) { ok = false; break; }
  }
  if (!ok){
    k_zero<<<(out_size+255)/256,256,0,stream>>>(outp, out_size);
    return;
  }
  const bool bigws = (ws_size >= WS_BIG*sizeof(float));

  const float* x   = (const float*)d_in[0];
  const float* W1  = (const float*)d_in[1];
  const float* b1  = (const float*)d_in[2];
  const float* g1  = (const float*)d_in[3];
  const float* bt1 = (const float*)d_in[4];
  const float* Wg  = (const float*)d_in[5];
  const float* bg  = (const float*)d_in[6];
  const float* gg  = (const float*)d_in[7];
  const float* btg = (const float*)d_in[8];
  const float* W2  = (const float*)d_in[9];
  const float* b2v = (const float*)d_in[10];
  const float* g2  = (const float*)d_in[11];
  const float* bt2 = (const float*)d_in[12];
  const float* Wf1 = (const float*)d_in[13];
  const float* bf1v= (const float*)d_in[14];
  const float* gf1 = (const float*)d_in[15];
  const float* btf1= (const float*)d_in[16];
  const float* Wf2 = (const float*)d_in[17];
  const float* bf2v= (const float*)d_in[18];
  const float* gf2 = (const float*)d_in[19];
  const float* btf2= (const float*)d_in[20];
  const float* alpha=(const float*)d_in[21];
  float* ws = (float*)d_ws;

  float* x0f  = ws + 0;
  float* hbuf = ws + 524288;
  float* xnb  = ws + 1048576;
  float* sqb  = ws + 1572864;
  float* partA= ws + 1581056;
  int*   idxf = (int*)(ws + 1712640);
  float* f0   = ws + 1786368;
  float* f1b  = ws + 2310656;
  float* Rbig = ws + 2834944;
  float* pdist = Rbig;
  int*   pidx  = (int*)(Rbig + (size_t)R1*SPLIT*9);
  float* gmaxb = Rbig;
  float* outt  = Rbig + 1048576;
  float* Y2    = Rbig + 1572864;
  float* partB = Rbig + 2097152;
  float* Yf2   = Rbig;
  float* Yg    = ws + WS_TOTAL;          // only used when bigws

  k_transpose<<<2048,256,0,stream>>>(x, x0f);
  float* feats[2] = {f0, f1b};
  for (int t=0; t<TT; t++){
    k_gemm1_stats<<<256,256,0,stream>>>(x0f, W1 + t*CCH*CCH, b1 + t*64, hbuf, partA);
    k_applynorm3<<<256,256,0,stream>>>(hbuf, partA, g1 + t*64, bt1 + t*64, xnb, sqb);
    k_knn<<<512,256,0,stream>>>(xnb, sqb, pdist, pidx);
    k_edge1<<<512,256,0,stream>>>(hbuf, pdist, pidx, Wg + t*C2*C2, bg + t*C2, idxf, partA,
                                  bigws ? Yg : hbuf, bigws ? 1 : 0);
    if (bigws){
      k_edge2m<<<512,256,0,stream>>>(Yg, partA, gg + t*C2, btg + t*C2, gmaxb);
    } else {
      k_edge2<<<512,256,0,stream>>>(hbuf, idxf, Wg + t*C2*C2, bg + t*C2,
                                    partA, gg + t*C2, btg + t*C2, gmaxb);
    }
    k_gemm2_stats<<<256,256,0,stream>>>(gmaxb, W2 + t*C2*CCH, b2v + t*64, Y2, partA);
    k_ffn1_fused<<<256,256,0,stream>>>(Y2, partA, g2 + t*64, bt2 + t*64, x0f, outt,
                                       Wf1 + t*CCH*C4, bf1v + t*C4, partB);
    k_ffn2_fused<<<256,256,0,stream>>>(outt, Wf1 + t*CCH*C4, bf1v + t*C4, partB,
                                       gf1 + t*C4, btf1 + t*C4,
                                       Wf2 + t*C4*CCH, bf2v + t*64, Yf2, partA);
    k_final<<<256,256,0,stream>>>(Yf2, partA, gf2 + t*64, btf2 + t*64, outt, feats[t]);
  }
  k_mix<<<4096,256,0,stream>>>(f0, f1b, alpha, outp);
}

// Round 17
// 1052.146 us; speedup vs baseline: 1.6884x; 1.2961x over previous
//
#include <hip/hip_runtime.h>
#include <math.h>

#define BB 2
#define CCH 64
#define NN 4096
#define KK 9
#define TT 2
#define C2 128
#define C4 256
#define R1 (BB*NN)        /* 8192  */
#define RG (BB*NN*KK)     /* 73728 */
#define SPLIT 16
#define CHUNK (NN/SPLIT)  /* 256 */
#define JT 128            /* j-tile rows staged in LDS */

#define WS_TOTAL 5194240ull
#define WS_BIG   (5194240ull + 9437184ull)   /* + Yg (RG*C2) */

__device__ __forceinline__ float gelu(float v){ return 0.5f*v*(1.f + erff(v*0.70710678118654752f)); }

__global__ void k_zero(float* __restrict__ o, int n){
  int i = blockIdx.x*256 + threadIdx.x;
  if (i < n) o[i] = 0.f;
}

// ---------------- transpose x (B,C,N) -> x0f (B,N,C) ----------------
__global__ void k_transpose(const float* __restrict__ x, float* __restrict__ x0f){
  int idx = blockIdx.x*256 + threadIdx.x;
  if (idx >= BB*NN*CCH) return;
  int c = idx & (CCH-1);
  int n = (idx >> 6) & (NN-1);
  int b = idx >> 18;
  x0f[idx] = x[(size_t)(b*CCH + c)*NN + n];
}

// ------ GEMM1 (64->64) + stats: tiled 2x4/thread, transposed-X LDS ------
__global__ void k_gemm1_stats(const float* __restrict__ X, const float* __restrict__ W,
                              const float* __restrict__ bias, float* __restrict__ Y,
                              float* __restrict__ part){
  __shared__ float xT[64*34];
  __shared__ float s1[1024], s2[1024];
  int tid = threadIdx.x;
  int r0 = blockIdx.x*32;
  #pragma unroll
  for (int u=0; u<2; u++){
    float4 v = ((const float4*)(X + (size_t)r0*64))[u*256+tid];
    int fi = (u*256+tid)*4;
    int r = fi >> 6, d = fi & 63;
    xT[(d+0)*34 + r] = v.x;
    xT[(d+1)*34 + r] = v.y;
    xT[(d+2)*34 + r] = v.z;
    xT[(d+3)*34 + r] = v.w;
  }
  __syncthreads();
  int tx = tid & 15, ty = tid >> 4;
  int c = tx*4, r = ty*2;
  float acc[2][4];
  #pragma unroll
  for (int i=0;i<2;i++){
    #pragma unroll
    for (int j=0;j<4;j++) acc[i][j] = 0.f;
  }
  for (int d=0; d<64; d++){
    float2 xv = *(const float2*)&xT[d*34 + r];
    float4 wv = *(const float4*)(W + d*64 + c);
    acc[0][0] = fmaf(xv.x, wv.x, acc[0][0]);
    acc[0][1] = fmaf(xv.x, wv.y, acc[0][1]);
    acc[0][2] = fmaf(xv.x, wv.z, acc[0][2]);
    acc[0][3] = fmaf(xv.x, wv.w, acc[0][3]);
    acc[1][0] = fmaf(xv.y, wv.x, acc[1][0]);
    acc[1][1] = fmaf(xv.y, wv.y, acc[1][1]);
    acc[1][2] = fmaf(xv.y, wv.z, acc[1][2]);
    acc[1][3] = fmaf(xv.y, wv.w, acc[1][3]);
  }
  float4 bz = *(const float4*)(bias + c);
  float bzv[4] = {bz.x, bz.y, bz.z, bz.w};
  float out0[4], out1[4];
  #pragma unroll
  for (int j=0;j<4;j++){
    out0[j] = acc[0][j] + bzv[j];
    out1[j] = acc[1][j] + bzv[j];
    s1[(c+j)*16+ty] = out0[j] + out1[j];
    s2[(c+j)*16+ty] = out0[j]*out0[j] + out1[j]*out1[j];
  }
  *(float4*)&Y[(size_t)(r0+r)*64 + c]   = make_float4(out0[0],out0[1],out0[2],out0[3]);
  *(float4*)&Y[(size_t)(r0+r+1)*64 + c] = make_float4(out1[0],out1[1],out1[2],out1[3]);
  __syncthreads();
  if (tid < 64){
    float sm=0.f, ss=0.f;
    #pragma unroll
    for (int q=0;q<16;q++){ sm += s1[tid*16+q]; ss += s2[tid*16+q]; }
    part[blockIdx.x*128 + tid] = sm;
    part[blockIdx.x*128 + 64 + tid] = ss;
  }
}

// ------ GEMM2 (128->64) + stats: tiled 2x4/thread, transposed-X LDS ------
__global__ void k_gemm2_stats(const float* __restrict__ X, const float* __restrict__ W,
                              const float* __restrict__ bias, float* __restrict__ Y,
                              float* __restrict__ part){
  __shared__ float xT[128*34];
  __shared__ float s1[1024], s2[1024];
  int tid = threadIdx.x;
  int r0 = blockIdx.x*32;
  #pragma unroll
  for (int u=0; u<4; u++){
    float4 v = ((const float4*)(X + (size_t)r0*128))[u*256+tid];
    int fi = (u*256+tid)*4;
    int r = fi >> 7, d = fi & 127;
    xT[(d+0)*34 + r] = v.x;
    xT[(d+1)*34 + r] = v.y;
    xT[(d+2)*34 + r] = v.z;
    xT[(d+3)*34 + r] = v.w;
  }
  __syncthreads();
  int tx = tid & 15, ty = tid >> 4;
  int c = tx*4, r = ty*2;
  float acc[2][4];
  #pragma unroll
  for (int i=0;i<2;i++){
    #pragma unroll
    for (int j=0;j<4;j++) acc[i][j] = 0.f;
  }
  for (int d=0; d<128; d++){
    float2 xv = *(const float2*)&xT[d*34 + r];
    float4 wv = *(const float4*)(W + d*64 + c);
    acc[0][0] = fmaf(xv.x, wv.x, acc[0][0]);
    acc[0][1] = fmaf(xv.x, wv.y, acc[0][1]);
    acc[0][2] = fmaf(xv.x, wv.z, acc[0][2]);
    acc[0][3] = fmaf(xv.x, wv.w, acc[0][3]);
    acc[1][0] = fmaf(xv.y, wv.x, acc[1][0]);
    acc[1][1] = fmaf(xv.y, wv.y, acc[1][1]);
    acc[1][2] = fmaf(xv.y, wv.z, acc[1][2]);
    acc[1][3] = fmaf(xv.y, wv.w, acc[1][3]);
  }
  float4 bz = *(const float4*)(bias + c);
  float bzv[4] = {bz.x, bz.y, bz.z, bz.w};
  float out0[4], out1[4];
  #pragma unroll
  for (int j=0;j<4;j++){
    out0[j] = acc[0][j] + bzv[j];
    out1[j] = acc[1][j] + bzv[j];
    s1[(c+j)*16+ty] = out0[j] + out1[j];
    s2[(c+j)*16+ty] = out0[j]*out0[j] + out1[j]*out1[j];
  }
  *(float4*)&Y[(size_t)(r0+r)*64 + c]   = make_float4(out0[0],out0[1],out0[2],out0[3]);
  *(float4*)&Y[(size_t)(r0+r+1)*64 + c] = make_float4(out1[0],out1[1],out1[2],out1[3]);
  __syncthreads();
  if (tid < 64){
    float sm=0.f, ss=0.f;
    #pragma unroll
    for (int q=0;q<16;q++){ sm += s1[tid*16+q]; ss += s2[tid*16+q]; }
    part[blockIdx.x*128 + tid] = sm;
    part[blockIdx.x*128 + 64 + tid] = ss;
  }
}

// ---------------- inline fin (G=256, Cc=64) + BN apply + row-normalize ------------
__global__ void k_applynorm3(float* __restrict__ h, const float* __restrict__ part,
                             const float* __restrict__ g, const float* __restrict__ bt,
                             float* __restrict__ xn, float* __restrict__ sq){
  __shared__ float scshL[128];
  __shared__ float s1[256], s2[256];
  int tid = threadIdx.x;
  {
    int c = tid & 63, sl = tid >> 6;
    float sm=0.f, ss=0.f;
    #pragma unroll 4
    for (int u=sl*64; u<sl*64+64; u++){ sm += part[u*128+c]; ss += part[u*128+64+c]; }
    s1[tid]=sm; s2[tid]=ss;
  }
  __syncthreads();
  if (tid < 64){
    float sm = s1[tid]+s1[64+tid]+s1[128+tid]+s1[192+tid];
    float ss = s2[tid]+s2[64+tid]+s2[128+tid]+s2[192+tid];
    float mean = sm/(float)R1;
    float var = fmaxf(ss/(float)R1 - mean*mean, 0.f);
    float sc = g[tid]*rsqrtf(var+1e-5f);
    scshL[tid] = sc; scshL[64+tid] = bt[tid] - mean*sc;
  }
  __syncthreads();
  int lane = tid & 63, w = tid >> 6;
  int r0 = blockIdx.x*32;
  for (int it=0; it<8; it++){
    int r = r0 + w*8 + it;
    float v = fmaf(h[(size_t)r*64+lane], scshL[lane], scshL[64+lane]);
    h[(size_t)r*64+lane] = v;
    float s2v = v*v;
    #pragma unroll
    for (int off=32; off; off>>=1) s2v += __shfl_xor(s2v, off, 64);
    float den = fmaxf(sqrtf(s2v), 1e-12f);
    float xv = v/den;
    xn[(size_t)r*64+lane] = xv;
    float t2 = xv*xv;
    #pragma unroll
    for (int off=32; off; off>>=1) t2 += __shfl_xor(t2, off, 64);
    if (lane==0) sq[r] = t2;
  }
}

// ---------------- top-9 streaming insert (strict <) ----------------
__device__ __forceinline__ void topk_insert(float d, int j, float* bd, int* bi,
                                            float& wd, int& wi){
  if (d < wd){
    bool done=false;
    #pragma unroll
    for (int q=0;q<9;q++){
      if (!done && bd[q]==wd && bi[q]==wi){ bd[q]=d; bi[q]=j; done=true; }
    }
    wd = bd[0]; wi = bi[0];
    #pragma unroll
    for (int q=1;q<9;q++){
      if (bd[q] > wd || (bd[q]==wd && bi[q] > wi)){ wd=bd[q]; wi=bi[q]; }
    }
  }
}

// ---------------- KNN: 1 i-row/thread (R13 structure, JT=128) ----------------
__global__ __launch_bounds__(256, 2) void k_knn(const float* __restrict__ xn,
                      const float* __restrict__ sq,
                      float* __restrict__ pd, int* __restrict__ pi_){
  __shared__ float xjL[JT*64];
  __shared__ float sqL[JT];
  int bx = blockIdx.x;
  int b     = bx >> 8;
  int ib    = (bx >> 4) & 15;
  int split = bx & 15;
  int tid = threadIdx.x;
  const float* xb = xn + (size_t)b*NN*64;
  const float* sqb = sq + (size_t)b*NN;
  int i = ib*256 + tid;
  float4 xi[16];
  {
    const float4* p = (const float4*)(xb + (size_t)i*64);
    #pragma unroll
    for (int q=0;q<16;q++) xi[q] = p[q];
  }
  #pragma unroll
  for (int q=0;q<16;q++){
    asm volatile("" : "+v"(xi[q].x), "+v"(xi[q].y), "+v"(xi[q].z), "+v"(xi[q].w));
  }
  float sqi = sqb[i];
  float bd[9]; int bi[9];
  #pragma unroll
  for (int q=0;q<9;q++){ bd[q]=INFINITY; bi[q]=0x7fffffff; }
  float wd=INFINITY; int wi=0x7fffffff;
  int jbase = split*CHUNK;
  for (int tile=0; tile<CHUNK/JT; tile++){
    int jt = jbase + tile*JT;
    __syncthreads();
    {
      const float4* src = (const float4*)(xb + (size_t)jt*64);
      float4* dst = (float4*)xjL;
      #pragma unroll
      for (int u=0; u<JT*16/256; u++) dst[u*256 + tid] = src[u*256 + tid];
      if (tid < JT) sqL[tid] = sqb[jt + tid];
    }
    __syncthreads();
    for (int jj=0; jj<JT; jj++){
      const float4* xj = (const float4*)(xjL + jj*64);
      float a0=0.f,a1=0.f,a2=0.f,a3=0.f;
      #pragma unroll
      for (int q=0;q<16;q++){
        float4 v = xj[q];
        a0 = fmaf(xi[q].x, v.x, a0);
        a1 = fmaf(xi[q].y, v.y, a1);
        a2 = fmaf(xi[q].z, v.z, a2);
        a3 = fmaf(xi[q].w, v.w, a3);
      }
      float dot = (a0+a1)+(a2+a3);
      int j = jt + jj;
      float d = sqi + sqL[jj] - 2.f*dot;
      topk_insert(d, j, bd, bi, wd, wi);
    }
  }
  size_t base = (((size_t)(b*NN + i))*SPLIT + split)*9;
  #pragma unroll
  for (int q=0;q<9;q++){ pd[base+q]=bd[q]; pi_[base+q]=bi[q]; }
}

// ------- edge pass 1: fused merge + edge-GEMM stats (+Yg store), float4 LDS -------
__global__ __launch_bounds__(256) void k_edge1(const float* __restrict__ h,
                        const float* __restrict__ pd, const int* __restrict__ pi_,
                        const float* __restrict__ Wg, const float* __restrict__ bg,
                        int* __restrict__ idxf, float* __restrict__ part,
                        float* __restrict__ Yg, int storeYg){
  __shared__ float dxAll[4*576];
  __shared__ float xiAll[4*64];
  __shared__ float sSum[512], sSq[512];
  int tid = threadIdx.x, lane = tid & 63, wv = tid >> 6;
  float* dxW = dxAll + wv*576;
  float* xiW = xiAll + wv*64;
  int c0 = lane, c1 = lane + 64;
  float bias0 = bg[c0], bias1 = bg[c1];
  float sm0=0.f, ss0=0.f, sm1=0.f, ss1=0.f;
  for (int u4=0; u4<4; u4++){
    int node = blockIdx.x*16 + wv*4 + u4;
    int b = node >> 12;
    size_t cb = (size_t)node*(SPLIT*9);
    float d0 = pd[cb+lane], d1 = pd[cb+64+lane], d2 = INFINITY;
    int   j0 = pi_[cb+lane], j1 = pi_[cb+64+lane], j2 = 0x7fffffff;
    if (lane < 16){ d2 = pd[cb+128+lane]; j2 = pi_[cb+128+lane]; }
    int kidx[9];
    #pragma unroll
    for (int s=0; s<9; s++){
      float ld = d0; int lj = j0;
      if (d1 < ld || (d1 == ld && j1 < lj)){ ld = d1; lj = j1; }
      if (d2 < ld || (d2 == ld && j2 < lj)){ ld = d2; lj = j2; }
      #pragma unroll
      for (int off=1; off<64; off<<=1){
        float od = __shfl_xor(ld, off, 64);
        int   oj = __shfl_xor(lj, off, 64);
        if (od < ld || (od == ld && oj < lj)){ ld = od; lj = oj; }
      }
      kidx[s] = lj & (NN-1);
      if (lane == 0) idxf[(size_t)node*9 + s] = lj & (NN-1);
      if (j0 == lj){ d0 = INFINITY; j0 = 0x7fffffff; }
      if (j1 == lj){ d1 = INFINITY; j1 = 0x7fffffff; }
      if (j2 == lj){ d2 = INFINITY; j2 = 0x7fffffff; }
    }
    float xi_l = h[(size_t)node*64 + lane];
    xiW[lane] = xi_l;
    #pragma unroll
    for (int k=0; k<9; k++)
      dxW[k*64+lane] = h[((size_t)(b*NN + kidx[k]))*64 + lane] - xi_l;
    // compute (float4-vectorized LDS reads)
    float common0 = bias0, common1 = bias1;
    const float4* xi4 = (const float4*)xiW;
    #pragma unroll 4
    for (int d4=0; d4<16; d4++){
      float4 xv = xi4[d4];
      int d = d4*4;
      common0 = fmaf(xv.x, Wg[(d+0)*C2+c0], common0);
      common0 = fmaf(xv.y, Wg[(d+1)*C2+c0], common0);
      common0 = fmaf(xv.z, Wg[(d+2)*C2+c0], common0);
      common0 = fmaf(xv.w, Wg[(d+3)*C2+c0], common0);
      common1 = fmaf(xv.x, Wg[(d+0)*C2+c1], common1);
      common1 = fmaf(xv.y, Wg[(d+1)*C2+c1], common1);
      common1 = fmaf(xv.z, Wg[(d+2)*C2+c1], common1);
      common1 = fmaf(xv.w, Wg[(d+3)*C2+c1], common1);
    }
    float a0[9], a1[9];
    #pragma unroll
    for (int k=0;k<9;k++){ a0[k]=0.f; a1[k]=0.f; }
    const float4* dx4 = (const float4*)dxW;
    for (int d4=0; d4<16; d4++){
      int d = d4*4;
      float w0v[4], w1v[4];
      #pragma unroll
      for (int i=0;i<4;i++){
        w0v[i] = Wg[(64+d+i)*C2+c0];
        w1v[i] = Wg[(64+d+i)*C2+c1];
      }
      #pragma unroll
      for (int k=0;k<9;k++){
        float4 dx = dx4[k*16+d4];
        a0[k] = fmaf(dx.x, w0v[0], a0[k]);
        a0[k] = fmaf(dx.y, w0v[1], a0[k]);
        a0[k] = fmaf(dx.z, w0v[2], a0[k]);
        a0[k] = fmaf(dx.w, w0v[3], a0[k]);
        a1[k] = fmaf(dx.x, w1v[0], a1[k]);
        a1[k] = fmaf(dx.y, w1v[1], a1[k]);
        a1[k] = fmaf(dx.z, w1v[2], a1[k]);
        a1[k] = fmaf(dx.w, w1v[3], a1[k]);
      }
    }
    #pragma unroll
    for (int k=0;k<9;k++){
      float v0 = common0 + a0[k], v1 = common1 + a1[k];
      sm0 += v0; ss0 += v0*v0; sm1 += v1; ss1 += v1*v1;
      if (storeYg){
        size_t yb = ((size_t)node*9 + k)*C2;
        Yg[yb + c0] = v0;
        Yg[yb + c1] = v1;
      }
    }
  }
  sSum[wv*128+lane] = sm0; sSum[wv*128+64+lane] = sm1;
  sSq [wv*128+lane] = ss0; sSq [wv*128+64+lane] = ss1;
  __syncthreads();
  if (tid < 128){
    float sm = sSum[tid]+sSum[128+tid]+sSum[256+tid]+sSum[384+tid];
    float ss = sSq[tid]+sSq[128+tid]+sSq[256+tid]+sSq[384+tid];
    part[blockIdx.x*256 + tid] = sm;
    part[blockIdx.x*256 + 128 + tid] = ss;
  }
}

// ------- edge pass 2 (materialized): inline fin + BN + gelu + max over Yg ---------
__global__ __launch_bounds__(256) void k_edge2m(const float* __restrict__ Yg,
                        const float* __restrict__ part, const float* __restrict__ gg,
                        const float* __restrict__ btg, float* __restrict__ gmax){
  __shared__ float scshL[256];
  __shared__ float s1[256], s2[256];
  int tid = threadIdx.x;
  {
    int cc = tid & 127, sl = tid >> 7;
    float sm=0.f, ss=0.f;
    #pragma unroll 4
    for (int u=sl*256; u<sl*256+256; u++){ sm += part[u*256+cc]; ss += part[u*256+128+cc]; }
    s1[tid]=sm; s2[tid]=ss;
  }
  __syncthreads();
  if (tid < 128){
    float sm = s1[tid]+s1[128+tid];
    float ss = s2[tid]+s2[128+tid];
    float mean = sm/(float)RG;
    float var = fmaxf(ss/(float)RG - mean*mean, 0.f);
    float sc = gg[tid]*rsqrtf(var+1e-5f);
    scshL[tid] = sc; scshL[128+tid] = btg[tid] - mean*sc;
  }
  __syncthreads();
  size_t base = (size_t)blockIdx.x*2048;
  for (int p=0; p<8; p++){
    size_t idx = base + p*256 + tid;
    int c = idx & 127;
    size_t node = idx >> 7;
    float sc = scshL[c], sh = scshL[128+c];
    size_t yb = node*9*C2 + c;
    float m = -INFINITY;
    #pragma unroll
    for (int k=0;k<9;k++){
      m = fmaxf(m, gelu(fmaf(Yg[yb + (size_t)k*C2], sc, sh)));
    }
    gmax[idx] = m;
  }
}

// ------- edge pass 2 (fallback): inline fin + recompute + BN + gelu + max ---------
__global__ __launch_bounds__(256) void k_edge2(const float* __restrict__ h,
                        const int* __restrict__ idxf,
                        const float* __restrict__ Wg, const float* __restrict__ bg,
                        const float* __restrict__ part, const float* __restrict__ gg,
                        const float* __restrict__ btg, float* __restrict__ gmax){
  __shared__ float dxAll[4*576];
  __shared__ float xiAll[4*64];
  __shared__ float scshL[256];
  __shared__ float s1[256], s2[256];
  int tid = threadIdx.x, lane = tid & 63, wv = tid >> 6;
  {
    int cc = tid & 127, sl = tid >> 7;
    float sm=0.f, ss=0.f;
    #pragma unroll 4
    for (int u=sl*256; u<sl*256+256; u++){ sm += part[u*256+cc]; ss += part[u*256+128+cc]; }
    s1[tid]=sm; s2[tid]=ss;
  }
  __syncthreads();
  if (tid < 128){
    float sm = s1[tid]+s1[128+tid];
    float ss = s2[tid]+s2[128+tid];
    float mean = sm/(float)RG;
    float var = fmaxf(ss/(float)RG - mean*mean, 0.f);
    float sc = gg[tid]*rsqrtf(var+1e-5f);
    scshL[tid] = sc; scshL[128+tid] = btg[tid] - mean*sc;
  }
  __syncthreads();
  float* dxW = dxAll + wv*576;
  float* xiW = xiAll + wv*64;
  int c0 = lane, c1 = lane + 64;
  float bias0 = bg[c0], bias1 = bg[c1];
  float sc0 = scshL[c0], sh0 = scshL[128+c0];
  float sc1 = scshL[c1], sh1 = scshL[128+c1];
  for (int u4=0; u4<4; u4++){
    int node = blockIdx.x*16 + wv*4 + u4;
    int b = node >> 12;
    int kidx[9];
    #pragma unroll
    for (int k=0;k<9;k++) kidx[k] = idxf[(size_t)node*9 + k] & (NN-1);
    float xi_l = h[(size_t)node*64 + lane];
    xiW[lane] = xi_l;
    #pragma unroll
    for (int k=0; k<9; k++)
      dxW[k*64+lane] = h[((size_t)(b*NN + kidx[k]))*64 + lane] - xi_l;
    float common0 = bias0, common1 = bias1;
    for (int d=0; d<64; d++){
      float xv = xiW[d];
      common0 = fmaf(xv, Wg[d*C2+c0], common0);
      common1 = fmaf(xv, Wg[d*C2+c1], common1);
    }
    float a0[9], a1[9];
    #pragma unroll
    for (int k=0;k<9;k++){ a0[k]=0.f; a1[k]=0.f; }
    for (int d=0; d<64; d++){
      float w0 = Wg[(64+d)*C2+c0], w1 = Wg[(64+d)*C2+c1];
      #pragma unroll
      for (int k=0;k<9;k++){
        float dxv = dxW[k*64+d];
        a0[k] = fmaf(dxv, w0, a0[k]);
        a1[k] = fmaf(dxv, w1, a1[k]);
      }
    }
    float m0 = -INFINITY, m1 = -INFINITY;
    #pragma unroll
    for (int k=0;k<9;k++){
      m0 = fmaxf(m0, gelu(fmaf(common0 + a0[k], sc0, sh0)));
      m1 = fmaxf(m1, gelu(fmaf(common1 + a1[k], sc1, sh1)));
    }
    gmax[(size_t)node*C2 + c0] = m0;
    gmax[(size_t)node*C2 + c1] = m1;
  }
}

// --- inline fin(G=256,Cc=64) + BN2 + residual + FFN1 GEMM (tiled 8x4) + stats ---
__global__ void k_ffn1_fused(const float* __restrict__ Y2, const float* __restrict__ part,
                             const float* __restrict__ g2, const float* __restrict__ bt2,
                             const float* __restrict__ x0f, float* __restrict__ outt,
                             const float* __restrict__ Wf1, const float* __restrict__ bf1,
                             float* __restrict__ partB){
  __shared__ float scshL[128];
  __shared__ float otT[64*36];
  __shared__ float s1[1024], s2[1024];
  int tid = threadIdx.x;
  int r0 = blockIdx.x*32;
  {
    int c = tid & 63, sl = tid >> 6;
    float sm=0.f, ss=0.f;
    #pragma unroll 4
    for (int u=sl*64; u<sl*64+64; u++){ sm += part[u*128+c]; ss += part[u*128+64+c]; }
    s1[tid]=sm; s2[tid]=ss;
  }
  __syncthreads();
  if (tid < 64){
    float sm = s1[tid]+s1[64+tid]+s1[128+tid]+s1[192+tid];
    float ss = s2[tid]+s2[64+tid]+s2[128+tid]+s2[192+tid];
    float mean = sm/(float)R1;
    float var = fmaxf(ss/(float)R1 - mean*mean, 0.f);
    float sc = g2[tid]*rsqrtf(var+1e-5f);
    scshL[tid] = sc; scshL[64+tid] = bt2[tid] - mean*sc;
  }
  __syncthreads();
  #pragma unroll
  for (int p=0; p<8; p++){
    int idx = p*256 + tid;
    int lr = idx >> 6, cc = idx & 63;
    size_t gi = (size_t)(r0+lr)*64 + cc;
    float v = fmaf(Y2[gi], scshL[cc], scshL[64+cc]) + x0f[gi];
    otT[cc*36 + lr] = v;
    outt[gi] = v;
  }
  __syncthreads();
  int tx = tid & 63, ty = tid >> 6;
  int c = tx*4, r = ty*8;
  float acc[8][4];
  #pragma unroll
  for (int i=0;i<8;i++){
    #pragma unroll
    for (int j=0;j<4;j++) acc[i][j]=0.f;
  }
  for (int d=0; d<64; d++){
    float4 xa = *(const float4*)&otT[d*36 + r];
    float4 xb = *(const float4*)&otT[d*36 + r + 4];
    float4 wv = *(const float4*)(Wf1 + d*256 + c);
    float xs[8] = {xa.x,xa.y,xa.z,xa.w, xb.x,xb.y,xb.z,xb.w};
    #pragma unroll
    for (int i=0;i<8;i++){
      acc[i][0] = fmaf(xs[i], wv.x, acc[i][0]);
      acc[i][1] = fmaf(xs[i], wv.y, acc[i][1]);
      acc[i][2] = fmaf(xs[i], wv.z, acc[i][2]);
      acc[i][3] = fmaf(xs[i], wv.w, acc[i][3]);
    }
  }
  float4 bz = *(const float4*)(bf1 + c);
  float bzv[4] = {bz.x, bz.y, bz.z, bz.w};
  #pragma unroll
  for (int j=0;j<4;j++){
    float cs=0.f, cq=0.f;
    #pragma unroll
    for (int i=0;i<8;i++){
      float v = acc[i][j] + bzv[j];
      cs += v; cq += v*v;
    }
    s1[(c+j)*4 + ty] = cs;
    s2[(c+j)*4 + ty] = cq;
  }
  __syncthreads();
  {
    float sm = s1[tid*4]+s1[tid*4+1]+s1[tid*4+2]+s1[tid*4+3];
    float ss = s2[tid*4]+s2[tid*4+1]+s2[tid*4+2]+s2[tid*4+3];
    partB[blockIdx.x*512 + tid] = sm;
    partB[blockIdx.x*512 + 256 + tid] = ss;
  }
}

// --- inline fin(Cc=256) + FFN1-recompute(8x4) + gelu + FFN2 GEMM(2x4) + stats ---
__global__ void k_ffn2_fused(const float* __restrict__ outt, const float* __restrict__ Wf1,
                             const float* __restrict__ bf1, const float* __restrict__ partB,
                             const float* __restrict__ gf1, const float* __restrict__ btf1,
                             const float* __restrict__ Wf2, const float* __restrict__ bf2,
                             float* __restrict__ Yf2, float* __restrict__ partA){
  __shared__ float scshL[512];
  __shared__ float otT[64*36];
  __shared__ float fT[256*36];
  __shared__ float s1[1024], s2[1024];
  int tid = threadIdx.x;
  int r0 = blockIdx.x*32;
  {
    float sm=0.f, ss=0.f;
    #pragma unroll 4
    for (int u=0; u<256; u++){ sm += partB[u*512+tid]; ss += partB[u*512+256+tid]; }
    float mean = sm/(float)R1;
    float var = fmaxf(ss/(float)R1 - mean*mean, 0.f);
    float sc = gf1[tid]*rsqrtf(var+1e-5f);
    scshL[tid] = sc; scshL[256+tid] = btf1[tid] - mean*sc;
  }
  #pragma unroll
  for (int p=0; p<8; p++){
    int idx = p*256 + tid;
    int lr = idx >> 6, cc = idx & 63;
    otT[cc*36 + lr] = outt[(size_t)r0*64 + idx];
  }
  __syncthreads();
  int tx = tid & 63, ty = tid >> 6;
  int c = tx*4, r = ty*8;
  {
    float acc[8][4];
    #pragma unroll
    for (int i=0;i<8;i++){
      #pragma unroll
      for (int j=0;j<4;j++) acc[i][j]=0.f;
    }
    for (int d=0; d<64; d++){
      float4 xa = *(const float4*)&otT[d*36 + r];
      float4 xb = *(const float4*)&otT[d*36 + r + 4];
      float4 wv = *(const float4*)(Wf1 + d*256 + c);
      float xs[8] = {xa.x,xa.y,xa.z,xa.w, xb.x,xb.y,xb.z,xb.w};
      #pragma unroll
      for (int i=0;i<8;i++){
        acc[i][0] = fmaf(xs[i], wv.x, acc[i][0]);
        acc[i][1] = fmaf(xs[i], wv.y, acc[i][1]);
        acc[i][2] = fmaf(xs[i], wv.z, acc[i][2]);
        acc[i][3] = fmaf(xs[i], wv.w, acc[i][3]);
      }
    }
    float4 bz = *(const float4*)(bf1 + c);
    float bzv[4] = {bz.x, bz.y, bz.z, bz.w};
    #pragma unroll
    for (int j=0;j<4;j++){
      float sc = scshL[c+j], sh = scshL[256+c+j];
      #pragma unroll
      for (int i=0;i<8;i++){
        float v = gelu(fmaf(acc[i][j] + bzv[j], sc, sh));
        fT[(c+j)*36 + r + i] = v;
      }
    }
  }
  __syncthreads();
  int tx2 = tid & 15, ty2 = tid >> 4;
  int c2 = tx2*4, r2 = ty2*2;
  float acc2[2][4];
  #pragma unroll
  for (int i=0;i<2;i++){
    #pragma unroll
    for (int j=0;j<4;j++) acc2[i][j]=0.f;
  }
  for (int d=0; d<256; d++){
    float2 xv = *(const float2*)&fT[d*36 + r2];
    float4 wv = *(const float4*)(Wf2 + d*64 + c2);
    acc2[0][0] = fmaf(xv.x, wv.x, acc2[0][0]);
    acc2[0][1] = fmaf(xv.x, wv.y, acc2[0][1]);
    acc2[0][2] = fmaf(xv.x, wv.z, acc2[0][2]);
    acc2[0][3] = fmaf(xv.x, wv.w, acc2[0][3]);
    acc2[1][0] = fmaf(xv.y, wv.x, acc2[1][0]);
    acc2[1][1] = fmaf(xv.y, wv.y, acc2[1][1]);
    acc2[1][2] = fmaf(xv.y, wv.z, acc2[1][2]);
    acc2[1][3] = fmaf(xv.y, wv.w, acc2[1][3]);
  }
  float4 b2 = *(const float4*)(bf2 + c2);
  float b2v[4] = {b2.x, b2.y, b2.z, b2.w};
  float out0[4], out1[4];
  #pragma unroll
  for (int j=0;j<4;j++){
    out0[j] = acc2[0][j] + b2v[j];
    out1[j] = acc2[1][j] + b2v[j];
    s1[(c2+j)*16 + ty2] = out0[j] + out1[j];
    s2[(c2+j)*16 + ty2] = out0[j]*out0[j] + out1[j]*out1[j];
  }
  *(float4*)&Yf2[(size_t)(r0+r2)*64 + c2]   = make_float4(out0[0],out0[1],out0[2],out0[3]);
  *(float4*)&Yf2[(size_t)(r0+r2+1)*64 + c2] = make_float4(out1[0],out1[1],out1[2],out1[3]);
  __syncthreads();
  if (tid < 64){
    float sm=0.f, ss=0.f;
    #pragma unroll
    for (int q=0;q<16;q++){ sm += s1[tid*16+q]; ss += s2[tid*16+q]; }
    partA[blockIdx.x*128 + tid] = sm;
    partA[blockIdx.x*128 + 64 + tid] = ss;
  }
}

// ---------------- inline fin(G=256,Cc=64) + BNf2 + residual -> feats[t] ------------
__global__ void k_final(const float* __restrict__ Yf2, const float* __restrict__ partA,
                        const float* __restrict__ gf2, const float* __restrict__ btf2,
                        const float* __restrict__ outt, float* __restrict__ feat){
  __shared__ float scshL[128];
  __shared__ float s1[256], s2[256];
  int tid = threadIdx.x;
  {
    int c = tid & 63, sl = tid >> 6;
    float sm=0.f, ss=0.f;
    #pragma unroll 4
    for (int u=sl*64; u<sl*64+64; u++){ sm += partA[u*128+c]; ss += partA[u*128+64+c]; }
    s1[tid]=sm; s2[tid]=ss;
  }
  __syncthreads();
  if (tid < 64){
    float sm = s1[tid]+s1[64+tid]+s1[128+tid]+s1[192+tid];
    float ss = s2[tid]+s2[64+tid]+s2[128+tid]+s2[192+tid];
    float mean = sm/(float)R1;
    float var = fmaxf(ss/(float)R1 - mean*mean, 0.f);
    float sc = gf2[tid]*rsqrtf(var+1e-5f);
    scshL[tid] = sc; scshL[64+tid] = btf2[tid] - mean*sc;
  }
  __syncthreads();
  size_t base = (size_t)blockIdx.x*2048;
  for (int p=0; p<8; p++){
    size_t idx = base + p*256 + tid;
    int cc = idx & 63;
    feat[idx] = fmaf(Yf2[idx], scshL[cc], scshL[64+cc]) + outt[idx];
  }
}

// ---------------- alpha-mix + transpose -> output (T,B,C,N) fp32 ----------------
__global__ void k_mix(const float* __restrict__ f0, const float* __restrict__ f1,
                      const float* __restrict__ alpha, float* __restrict__ outv){
  int idx = blockIdx.x*256 + threadIdx.x;
  if (idx >= TT*BB*CCH*NN) return;
  int n = idx & (NN-1);
  int c = (idx >> 12) & 63;
  int b = (idx >> 18) & 1;
  int i = idx >> 19;
  float a0 = alpha[i*TT + 0];
  float a1 = alpha[i*TT + 1];
  size_t fi = ((size_t)(b*NN + n))*64 + c;
  outv[idx] = a0*f0[fi] + a1*f1[fi];
}

extern "C" void kernel_launch(void* const* d_in, const int* in_sizes, int n_in,
                              void* d_out, int out_size, void* d_ws, size_t ws_size,
                              hipStream_t stream){
  float* outp = (float*)d_out;

  static const int expect[22] = {
    524288, 8192, 128, 128, 128, 32768, 256, 256, 256, 16384, 128, 128, 128,
    32768, 512, 512, 512, 32768, 128, 128, 128, 4
  };
  bool ok = (n_in == 22) && (out_size == TT*BB*CCH*NN) &&
            (ws_size >= WS_TOTAL*sizeof(float));
  if (ok){
    for (int i=0;i<22;i++) if (in_sizes[i] != expect[i]) { ok = false; break; }
  }
  if (!ok){
    k_zero<<<(out_size+255)/256,256,0,stream>>>(outp, out_size);
    return;
  }
  const bool bigws = (ws_size >= WS_BIG*sizeof(float));

  const float* x   = (const float*)d_in[0];
  const float* W1  = (const float*)d_in[1];
  const float* b1  = (const float*)d_in[2];
  const float* g1  = (const float*)d_in[3];
  const float* bt1 = (const float*)d_in[4];
  const float* Wg  = (const float*)d_in[5];
  const float* bg  = (const float*)d_in[6];
  const float* gg  = (const float*)d_in[7];
  const float* btg = (const float*)d_in[8];
  const float* W2  = (const float*)d_in[9];
  const float* b2v = (const float*)d_in[10];
  const float* g2  = (const float*)d_in[11];
  const float* bt2 = (const float*)d_in[12];
  const float* Wf1 = (const float*)d_in[13];
  const float* bf1v= (const float*)d_in[14];
  const float* gf1 = (const float*)d_in[15];
  const float* btf1= (const float*)d_in[16];
  const float* Wf2 = (const float*)d_in[17];
  const float* bf2v= (const float*)d_in[18];
  const float* gf2 = (const float*)d_in[19];
  const float* btf2= (const float*)d_in[20];
  const float* alpha=(const float*)d_in[21];
  float* ws = (float*)d_ws;

  float* x0f  = ws + 0;
  float* hbuf = ws + 524288;
  float* xnb  = ws + 1048576;
  float* sqb  = ws + 1572864;
  float* partA= ws + 1581056;
  int*   idxf = (int*)(ws + 1712640);
  float* f0   = ws + 1786368;
  float* f1b  = ws + 2310656;
  float* Rbig = ws + 2834944;
  float* pdist = Rbig;
  int*   pidx  = (int*)(Rbig + (size_t)R1*SPLIT*9);
  float* gmaxb = Rbig;
  float* outt  = Rbig + 1048576;
  float* Y2    = Rbig + 1572864;
  float* partB = Rbig + 2097152;
  float* Yf2   = Rbig;
  float* Yg    = ws + WS_TOTAL;

  k_transpose<<<2048,256,0,stream>>>(x, x0f);
  float* feats[2] = {f0, f1b};
  for (int t=0; t<TT; t++){
    k_gemm1_stats<<<256,256,0,stream>>>(x0f, W1 + t*CCH*CCH, b1 + t*64, hbuf, partA);
    k_applynorm3<<<256,256,0,stream>>>(hbuf, partA, g1 + t*64, bt1 + t*64, xnb, sqb);
    k_knn<<<512,256,0,stream>>>(xnb, sqb, pdist, pidx);
    k_edge1<<<512,256,0,stream>>>(hbuf, pdist, pidx, Wg + t*C2*C2, bg + t*C2, idxf, partA,
                                  bigws ? Yg : hbuf, bigws ? 1 : 0);
    if (bigws){
      k_edge2m<<<512,256,0,stream>>>(Yg, partA, gg + t*C2, btg + t*C2, gmaxb);
    } else {
      k_edge2<<<512,256,0,stream>>>(hbuf, idxf, Wg + t*C2*C2, bg + t*C2,
                                    partA, gg + t*C2, btg + t*C2, gmaxb);
    }
    k_gemm2_stats<<<256,256,0,stream>>>(gmaxb, W2 + t*C2*CCH, b2v + t*64, Y2, partA);
    k_ffn1_fused<<<256,256,0,stream>>>(Y2, partA, g2 + t*64, bt2 + t*64, x0f, outt,
                                       Wf1 + t*CCH*C4, bf1v + t*C4, partB);
    k_ffn2_fused<<<256,256,0,stream>>>(outt, Wf1 + t*CCH*C4, bf1v + t*C4, partB,
                                       gf1 + t*C4, btf1 + t*C4,
                                       Wf2 + t*C4*CCH, bf2v + t*64, Yf2, partA);
    k_final<<<256,256,0,stream>>>(Yf2, partA, gf2 + t*64, btf2 + t*64, outt, feats[t]);
  }
  k_mix<<<4096,256,0,stream>>>(f0, f1b, alpha, outp);
}